// Round 9
// baseline (1188.455 us; speedup 1.0000x reference)
//
#include <hip/hip_runtime.h>
#include <hip/hip_bf16.h>
#include <hip/hip_fp16.h>

// ---------------------------------------------------------------------------
// GCN forward:  per layer  h' = ReLU( (Â h) @ W + b ),  aggregate-first.
// Node features stored fp16 PRE-SCALED by dis[i]:  hs[i] = dis[i]*h[i]
//   -> aggregation is a pure gather-SUM: a[i] = dis[i]*(hs[i] + sum hs[s])
// R17: 8-way channel slice, SLICE-MAJOR layout, XCD-pinned (bid&7 -> XCD).
//   Per-XCD gather footprint 3.2MB -> L2-resident (FETCH 159->32MB).
// R18: edge lists padded to x8 (phantom node N) + dwordx4 u16 index loads +
//   prefetch + 8-deep gather pipeline.
// R19: XCD-localized CSR scatter (write-merge in one L2).
// R23: edge binning in node space (translate_bin + csr_fill2): csr phase off
//   the leader board. [R20-R22 perm-space arc reverted: net negative.]
// R24: aggregate still leader (41us, VALUBusy 43%, nothing saturated) = wave
//   iterates to MAX of 16 nodes' trip counts (~1.6x mean). Minimal fix:
//   ORDER-INDIRECTION. order[] = nodes counting-sorted by ceil(deg/8)
//   bucket (3 tiny kernels); aggregate processes node=order[slot]. All
//   arrays stay original-space: only cost = one broadcast order read +
//   scattered A writes (inside own L2-resident slice -> merge; NT dropped).
// R15 GEMM: A-STATIONARY, 64-row LDS tile (stride K+40), ONE barrier,
// barrier-free K-loop, B direct from global (L2-hot). Layer-3 fuses pool.
// ---------------------------------------------------------------------------

#define THREADS 256

typedef _Float16 f16x8 __attribute__((ext_vector_type(8)));
typedef float    f32x4 __attribute__((ext_vector_type(4)));
typedef unsigned short u16x8 __attribute__((ext_vector_type(8)));

// ---------------- setup kernels ----------------

// degree histogram (i<E) + graph offsets from sorted batch (i<N), one launch
__global__ void degree_goff_kernel(const int* __restrict__ col, int* __restrict__ deg, int E,
                                   const int* __restrict__ batch, int* __restrict__ goff,
                                   int N, int G) {
    int i = blockIdx.x * THREADS + threadIdx.x;
    if (i < E) atomicAdd(&deg[col[i]], 1);
    if (i < N) {
        int b1 = batch[i];
        int b0 = (i == 0) ? -1 : batch[i - 1];
        for (int g = b0 + 1; g <= b1; ++g) goff[g] = i;
        if (i == N - 1) {
            for (int g = b1 + 1; g <= G; ++g) goff[g] = N;
        }
    }
}

// count nodes per degree bucket (64 buckets of ceil(deg/8))
__global__ void bucketcnt_kernel(const int* __restrict__ deg, int* __restrict__ bcnt, int N) {
    int i = blockIdx.x * THREADS + threadIdx.x;
    if (i < N) atomicAdd(&bcnt[min((deg[i] + 7) >> 3, 63)], 1);
}

// exclusive scan of 64 bucket counts, one wave
__global__ void bucketscan_kernel(int* __restrict__ b) {
    int lane = threadIdx.x;
    int v = b[lane];
    int inc = v;
    #pragma unroll
    for (int d = 1; d < 64; d <<= 1) {
        int t = __shfl_up(inc, d);
        if (lane >= d) inc += t;
    }
    b[lane] = inc - v;   // exclusive
}

// place nodes into degree-ordered list (bcnt holds running positions)
__global__ void place_kernel(const int* __restrict__ deg, int* __restrict__ bcnt,
                             int* __restrict__ order, int N) {
    int i = blockIdx.x * THREADS + threadIdx.x;
    if (i < N) {
        int pos = atomicAdd(&bcnt[min((deg[i] + 7) >> 3, 63)], 1);
        order[pos] = i;
    }
}

// scan phase A: per-block (1024 elems) exclusive scan of PADDED degrees
// (pad to multiple of 8) + block sum; also dis from REAL degree.
__global__ __launch_bounds__(256) void scanA_kernel(
    const int* __restrict__ in, int* __restrict__ out, int* __restrict__ bsum,
    float* __restrict__ dis, int n) {
    __shared__ int wsum[4];
    int i0 = blockIdx.x * 1024 + threadIdx.x * 4;
    int lane = threadIdx.x & 63, wid = threadIdx.x >> 6;
    int v0 = 0, v1 = 0, v2 = 0, v3 = 0;
    if (i0 + 3 < n) {
        int4 v = *(const int4*)&in[i0];
        v0 = v.x; v1 = v.y; v2 = v.z; v3 = v.w;
    } else {
        if (i0 + 0 < n) v0 = in[i0 + 0];
        if (i0 + 1 < n) v1 = in[i0 + 1];
        if (i0 + 2 < n) v2 = in[i0 + 2];
        if (i0 + 3 < n) v3 = in[i0 + 3];
    }
    // dis = rsqrt(deg+1) from real degree
    if (i0 + 0 < n) dis[i0 + 0] = rsqrtf((float)(v0 + 1));
    if (i0 + 1 < n) dis[i0 + 1] = rsqrtf((float)(v1 + 1));
    if (i0 + 2 < n) dis[i0 + 2] = rsqrtf((float)(v2 + 1));
    if (i0 + 3 < n) dis[i0 + 3] = rsqrtf((float)(v3 + 1));
    // pad degrees to multiple of 8 for the scan
    v0 = (v0 + 7) & ~7; v1 = (v1 + 7) & ~7;
    v2 = (v2 + 7) & ~7; v3 = (v3 + 7) & ~7;
    int s = v0 + v1 + v2 + v3;
    int inc = s;
    #pragma unroll
    for (int d = 1; d < 64; d <<= 1) {
        int t = __shfl_up(inc, d);
        if (lane >= d) inc += t;
    }
    if (lane == 63) wsum[wid] = inc;
    __syncthreads();
    int add = 0;
    for (int w = 0; w < wid; ++w) add += wsum[w];
    int ex = add + inc - s;
    if (i0 + 0 < n) out[i0 + 0] = ex;
    if (i0 + 1 < n) out[i0 + 1] = ex + v0;
    if (i0 + 2 < n) out[i0 + 2] = ex + v0 + v1;
    if (i0 + 3 < n) out[i0 + 3] = ex + v0 + v1 + v2;
    if (threadIdx.x == 255) bsum[blockIdx.x] = add + inc;  // block total
}

// scan phase B: 1 wave scans <=64 block sums; writes grand total to out[n].
__global__ void scanB_kernel(int* __restrict__ bsum, int* __restrict__ total_slot, int nb) {
    int lane = threadIdx.x;
    int v = (lane < nb) ? bsum[lane] : 0;
    int inc = v;
    #pragma unroll
    for (int d = 1; d < 64; d <<= 1) {
        int t = __shfl_up(inc, d);
        if (lane >= d) inc += t;
    }
    if (lane < nb) bsum[lane] = inc - v;   // exclusive
    if (lane == 63) *total_slot = inc;
}

// per-slice REAL edge counts: 8 blocks; block s sums deg over its node range
__global__ __launch_bounds__(256) void slicecnt_kernel(
    const int* __restrict__ deg, int* __restrict__ scnt, int N) {
    __shared__ int wsum[4];
    int s = blockIdx.x;
    int SL = (N + 7) >> 3;
    int lo = s * SL, hi = min(N, lo + SL);
    int acc = 0;
    for (int i = lo + (int)threadIdx.x; i < hi; i += 256) acc += deg[i];
    #pragma unroll
    for (int d = 1; d < 64; d <<= 1) acc += __shfl_xor(acc, d);
    int lane = threadIdx.x & 63, wid = threadIdx.x >> 6;
    if (lane == 0) wsum[wid] = acc;
    __syncthreads();
    if (threadIdx.x == 0) scnt[s] = wsum[0] + wsum[1] + wsum[2] + wsum[3];
}

// scan 8 slice counts -> binoff[0..8], init bcur
__global__ void scan8_kernel(const int* __restrict__ scnt, int* __restrict__ binoff,
                             int* __restrict__ bcur) {
    if (threadIdx.x == 0 && blockIdx.x == 0) {
        int cum = 0;
        for (int s = 0; s < 8; ++s) { binoff[s] = cum; bcur[s] = cum; cum += scnt[s]; }
        binoff[8] = cum;
    }
}

// LDS-partition edges into 8 per-slice bins (u32 = col | row<<16, N<65536).
// One pass over int edges (read ONCE); dense ~1KB bulk appends per bin.
__global__ __launch_bounds__(256) void translate_bin_kernel(
    const int* __restrict__ row, const int* __restrict__ col,
    unsigned int* __restrict__ bins, int* __restrict__ bcur, int E, int N) {
    __shared__ unsigned int lent[2048];
    __shared__ int lhist[8], lbase[8], gbase[8], lpos[8];
    int t = threadIdx.x;
    if (t < 8) lhist[t] = 0;
    __syncthreads();
    int SL = (N + 7) >> 3;
    int e0 = blockIdx.x * 2048 + t * 8;
    unsigned int ent[8]; int sl[8];
    int n = E - e0; if (n < 0) n = 0; if (n > 8) n = 8;
    if (n == 8) {
        int4 c0 = *(const int4*)&col[e0];
        int4 c1 = *(const int4*)&col[e0 + 4];
        int4 r0 = *(const int4*)&row[e0];
        int4 r1 = *(const int4*)&row[e0 + 4];
        int cs[8] = {c0.x, c0.y, c0.z, c0.w, c1.x, c1.y, c1.z, c1.w};
        int rs[8] = {r0.x, r0.y, r0.z, r0.w, r1.x, r1.y, r1.z, r1.w};
        #pragma unroll
        for (int j = 0; j < 8; ++j) {
            sl[j] = cs[j] / SL;
            ent[j] = (unsigned int)cs[j] | ((unsigned int)rs[j] << 16);
            atomicAdd(&lhist[sl[j]], 1);
        }
    } else {
        for (int j = 0; j < n; ++j) {
            int c = col[e0 + j], r = row[e0 + j];
            sl[j] = c / SL;
            ent[j] = (unsigned int)c | ((unsigned int)r << 16);
            atomicAdd(&lhist[sl[j]], 1);
        }
    }
    __syncthreads();
    if (t == 0) {
        int cum = 0;
        #pragma unroll
        for (int s = 0; s < 8; ++s) { lbase[s] = cum; cum += lhist[s]; }
    }
    __syncthreads();
    if (t < 8) { gbase[t] = atomicAdd(&bcur[t], lhist[t]); lpos[t] = lbase[t]; }
    __syncthreads();
    for (int j = 0; j < n; ++j) {
        int p = atomicAdd(&lpos[sl[j]], 1);
        lent[p] = ent[j];
    }
    __syncthreads();
    int total = lbase[7] + lhist[7];
    for (int k = t; k < total; k += 256) {
        unsigned int e = lent[k];
        int s = 0;
        #pragma unroll
        for (int b = 1; b < 8; ++b) s = (k >= lbase[b]) ? b : s;
        bins[gbase[s] + (k - lbase[s])] = e;
    }
}

// fill phantom pad slots [offs[c]+deg[c], offs[c+1]) with node id N.
// XCD-localized; runs after convert (offs final), before csr_fill2 (deg intact).
__global__ __launch_bounds__(256) void padfill_x_kernel(
    const int* __restrict__ offs, const int* __restrict__ deg,
    unsigned short* __restrict__ srcs, int N) {
    int slice = blockIdx.x & 7;
    int SL = (N + 7) >> 3;
    int node = slice * SL + (int)(blockIdx.x >> 3) * THREADS + threadIdx.x;
    int nhi = min(N, slice * SL + SL);
    if (node >= nhi) return;
    int s = offs[node] + deg[node], e = offs[node + 1];
    for (int i = s; i < e; ++i) srcs[i] = (unsigned short)N;
}

// CSR scatter phase 2: block bid&7 = slice = XCD; streams ONLY its slice's
// bin (dense u32, no duplication), scatters into its L2-resident srcs slice
// -> full-line write merge. Grid-stride handles skew. deg is the countdown.
__global__ __launch_bounds__(256) void csr_fill2_kernel(
    const unsigned int* __restrict__ bins, const int* __restrict__ binoff,
    const int* __restrict__ offs, int* __restrict__ deg,
    unsigned short* __restrict__ srcs, int CPS) {
    int slice = blockIdx.x & 7;
    int chunk = blockIdx.x >> 3;
    int lo = binoff[slice], hi = binoff[slice + 1];
    for (int base = lo + chunk * 2048; base < hi; base += CPS * 2048) {
        int i0 = base + (int)threadIdx.x * 8;
        #pragma unroll
        for (int j = 0; j < 8; ++j) {
            int i = i0 + j;
            if (i < hi) {
                unsigned int e = bins[i];
                int c = (int)(e & 0xffffu);
                int r = (int)(e >> 16);
                int old = atomicSub(&deg[c], 1);
                srcs[offs[c] + old - 1] = (unsigned short)r;
            }
        }
    }
}

// merged: scanC (offs += bsum) + x fp32->fp16*dis (slice-major, stride N+1)
// + W1/W2/W3 -> fp16^T + phantom-row zeroing for Xs and Hs.
__global__ void convert_kernel(
    int* __restrict__ offs, const int* __restrict__ bsum, int Nfix,
    const float* __restrict__ X, const float* __restrict__ dis,
    _Float16* __restrict__ Xs, int total8, int IC,
    const float* __restrict__ W1, _Float16* __restrict__ W1t, int k1,   // k1=IC
    const float* __restrict__ W2, _Float16* __restrict__ W2t,
    const float* __restrict__ W3, _Float16* __restrict__ W3t,
    _Float16* __restrict__ Hs) {
    int i = blockIdx.x * THREADS + threadIdx.x;
    if (i < Nfix) {                         // scanC: add scanned block offsets
        offs[i] += bsum[i >> 10];
        return;
    }
    int j = i - Nfix;
    int Ms = Nfix + 1;                      // row stride incl. phantom
    if (j < total8) {
        int idx = j * 8;
        int node = idx / IC;
        int ch0  = idx % IC;
        float d = dis[node];
        float4 a = *(const float4*)&X[idx];
        float4 b = *(const float4*)&X[idx + 4];
        f16x8 o;
        o[0] = (_Float16)(d * a.x); o[1] = (_Float16)(d * a.y);
        o[2] = (_Float16)(d * a.z); o[3] = (_Float16)(d * a.w);
        o[4] = (_Float16)(d * b.x); o[5] = (_Float16)(d * b.y);
        o[6] = (_Float16)(d * b.z); o[7] = (_Float16)(d * b.w);
        int sw = IC >> 3;                   // slice width in f16 (IC=128 -> 16)
        int slice = ch0 / sw, within = ch0 % sw;
        *(f16x8*)&Xs[((size_t)slice * Ms + node) * sw + within] = o;
        return;
    }
    j -= total8;
    int n1 = k1 * 256;
    if (j < n1) {                 // W1 [k1 x 256] -> W1t [256 x k1]
        int k = j >> 8, n = j & 255;
        W1t[n * k1 + k] = (_Float16)W1[j];
        return;
    }
    j -= n1;
    if (j < 65536) {              // W2 [256 x 256]
        int k = j >> 8, n = j & 255;
        W2t[n * 256 + k] = (_Float16)W2[j];
        return;
    }
    j -= 65536;
    if (j < 65536) {              // W3
        int k = j >> 8, n = j & 255;
        W3t[n * 256 + k] = (_Float16)W3[j];
        return;
    }
    j -= 65536;
    {   // zero phantom rows: Xs 8 slices x (IC/8) f16, Hs 8 slices x 32 f16
        int swx = IC >> 3;
        int nx = 8 * swx;
        if (j < nx) {
            int slice = j / swx, wi = j % swx;
            Xs[((size_t)slice * Ms + Nfix) * swx + wi] = (_Float16)0.f;
            return;
        }
        j -= nx;
        if (j < 256) {
            int slice = j >> 5, wi = j & 31;
            Hs[((size_t)slice * Ms + Nfix) * 32 + wi] = (_Float16)0.f;
        }
    }
}

// ---- aggregation: a[i] = dis[i] * ( hs[i] + sum_{s in nbr} hs[s] ) ----------
// 8-way slice-major, XCD-pinned (bid&7 = slice = XCD; slice L2-resident).
// R24: node = order[slot] (degree-ordered) -> waves hold nodes of identical
// trip-count bucket -> no intra-wave divergence. Padded edge lists (x8,
// phantom node N): indices load as one dwordx4 (8 x u16), prefetched one
// iteration ahead; 8 gathers in flight. fp32 accumulate. Output writes are
// scattered 64B granules inside this XCD's own L2-resident slice (normal
// stores so they merge in L2).

template<int CH>   // full channel count: 128 or 256
__global__ __launch_bounds__(256) void aggregate_slice_kernel(
    const _Float16* __restrict__ X, const int* __restrict__ offs,
    const unsigned short* __restrict__ srcs, const float* __restrict__ dis,
    const int* __restrict__ order, _Float16* __restrict__ A, int N) {
    constexpr int LPN = CH / 64;          // f16x8 lanes per node per slice (2 / 4)
    constexpr int NPB = 256 / LPN;        // nodes per block (128 / 64)
    int bid   = blockIdx.x;
    int slice = bid & 7;                  // round-robin -> XCD id
    int tile  = bid >> 3;
    int slot  = tile * NPB + threadIdx.x / LPN;
    if (slot >= N) return;
    int node = order[slot];               // degree-ordered (broadcast read)
    int lane = threadIdx.x % LPN;
    size_t Ms = (size_t)N + 1;            // row stride incl. phantom
    const f16x8* Xv = (const f16x8*)X + (size_t)slice * Ms * LPN;
    f16x8 self = Xv[(size_t)node * LPN + lane];
    float acc[8], acc2[8];
    #pragma unroll
    for (int j = 0; j < 8; ++j) { acc[j] = (float)self[j]; acc2[j] = 0.f; }
    int s = offs[node], e = offs[node + 1];
    int nit = (e - s) >> 3;               // padded: always a multiple of 8
    if (nit > 0) {
        const u16x8* ip = (const u16x8*)&srcs[s];   // 16B-aligned (s % 8 == 0)
        u16x8 idx = ip[0];
        for (int it = 0; it < nit; ++it) {
            u16x8 nxt = ip[min(it + 1, nit - 1)];   // prefetch next 8 indices
            f16x8 v0 = Xv[(size_t)idx[0] * LPN + lane];
            f16x8 v1 = Xv[(size_t)idx[1] * LPN + lane];
            f16x8 v2 = Xv[(size_t)idx[2] * LPN + lane];
            f16x8 v3 = Xv[(size_t)idx[3] * LPN + lane];
            f16x8 v4 = Xv[(size_t)idx[4] * LPN + lane];
            f16x8 v5 = Xv[(size_t)idx[5] * LPN + lane];
            f16x8 v6 = Xv[(size_t)idx[6] * LPN + lane];
            f16x8 v7 = Xv[(size_t)idx[7] * LPN + lane];
            #pragma unroll
            for (int j = 0; j < 8; ++j) {
                acc[j]  += ((float)v0[j] + (float)v2[j]) + ((float)v4[j] + (float)v6[j]);
                acc2[j] += ((float)v1[j] + (float)v3[j]) + ((float)v5[j] + (float)v7[j]);
            }
            idx = nxt;
        }
    }
    float dn = dis[node];
    f16x8 o;
    #pragma unroll
    for (int j = 0; j < 8; ++j) o[j] = (_Float16)(dn * (acc[j] + acc2[j]));
    f16x8* Av = (f16x8*)A + (size_t)slice * Ms * LPN;
    Av[(size_t)node * LPN + lane] = o;
}

// ---- A-STATIONARY GEMM: H[m,:256] = relu( A[m,:K] @ W^T + bias ) -----------
// A is slice-major [8][Ms][K/8] (Ms = N+1 incl. phantom). Staged into LDS as
// row-major [64][K] (k = seg*8 identity), MFMA loop unchanged. 64-row tile,
// stride K+40, ONE barrier, barrier-free K-loop, B direct from global.
// MODE 1: write H (slice-major, dscaled). MODE 2: fused mean-pool epilogue.

template<int K, int MODE>
__global__ __launch_bounds__(256) void gemm_as_kernel(
    const _Float16* __restrict__ A, const _Float16* __restrict__ Bt,
    const float* __restrict__ bias, const float* __restrict__ dscale,
    _Float16* __restrict__ H, float* __restrict__ pooled,
    const int* __restrict__ batch, int M, int Ms) {
    constexpr int LSA = K + 40;               // ≡ 40 mod 64 -> even bank spread
    constexpr int KC = K / 32;
    constexpr int SPR = K / 8;                // 16B segs per row
    constexpr int SPS = K / 64;               // segs per slice (2 / 4)
    constexpr int SW  = K / 8;                // f16 per slice (16 / 32)
    __shared__ _Float16 As[64 * LSA];
    int tid = threadIdx.x;
    int m0 = blockIdx.x * 64;

    // stage A tile once (slice-major source; contiguous 64B runs per slice)
    {
        constexpr int RPI = 256 / SPR;        // 8 rows/iter (K=256), 16 (K=128)
        int r_in = tid % RPI;                 // consecutive lanes -> distinct rows
        int seg  = tid / RPI;
        int slice = seg / SPS, sub = seg % SPS;
        #pragma unroll
        for (int it = 0; it < 64 / RPI; ++it) {
            int r = it * RPI + r_in;
            int gr = m0 + r;
            uint4 v = make_uint4(0, 0, 0, 0);
            if (gr < M) v = *(const uint4*)&A[((size_t)slice * Ms + gr) * SW + sub * 8];
            *(uint4*)&As[r * LSA + seg * 8] = v;
        }
    }
    __syncthreads();

    int wid = tid >> 6, lane = tid & 63;
    int l16 = lane & 15, quad = lane >> 4;
    int wn = wid * 64;                        // this wave's 64 output cols

    f32x4 acc[4][4] = {};
    const _Float16* Bbase = Bt + (size_t)(wn + l16) * K + quad * 8;

    #pragma unroll
    for (int kc = 0; kc < KC; ++kc) {
        f16x8 bh[4];
        #pragma unroll
        for (int ni = 0; ni < 4; ++ni)
            bh[ni] = *(const f16x8*)&Bbase[(size_t)(ni * 16) * K + kc * 32];
        #pragma unroll
        for (int mi = 0; mi < 4; ++mi) {
            f16x8 ah = *(const f16x8*)&As[(mi * 16 + l16) * LSA + kc * 32 + quad * 8];
            #pragma unroll
            for (int ni = 0; ni < 4; ++ni)
                acc[mi][ni] = __builtin_amdgcn_mfma_f32_16x16x32_f16(ah, bh[ni], acc[mi][ni], 0, 0, 0);
        }
    }

    #pragma unroll
    for (int mi = 0; mi < 4; ++mi) {
        int rbase = m0 + mi * 16;
        int g0 = 0, g15 = 0;
        if (MODE == 2) {
            g0  = batch[min(rbase, M - 1)];
            g15 = batch[min(rbase + 15, M - 1)];
        }
        #pragma unroll
        for (int ni = 0; ni < 4; ++ni) {
            int col = wn + ni * 16 + l16;
            float bv = bias[col];
            if (MODE == 1) {
                // slice-major H: slice = col>>5 (256 cols, 32 f16/slice)
                size_t hbase = (size_t)(col >> 5) * Ms * 32 + (col & 31);
                #pragma unroll
                for (int r = 0; r < 4; ++r) {
                    int grow = rbase + quad * 4 + r;
                    if (grow < M) {
                        float v = fmaxf(acc[mi][ni][r] + bv, 0.f) * dscale[grow];
                        H[hbase + (size_t)grow * 32] = (_Float16)v;
                    }
                }
            } else {  // MODE == 2: fused mean-pool accumulation
                if (g0 == g15) {
                    float p = 0.f;
                    #pragma unroll
                    for (int r = 0; r < 4; ++r) {
                        int grow = rbase + quad * 4 + r;
                        float v = fmaxf(acc[mi][ni][r] + bv, 0.f);
                        p += (grow < M) ? v : 0.f;
                    }
                    p += __shfl_xor(p, 16);
                    p += __shfl_xor(p, 32);
                    if (quad == 0) atomicAdd(&pooled[g0 * 256 + col], p);
                } else {
                    #pragma unroll
                    for (int r = 0; r < 4; ++r) {
                        int grow = rbase + quad * 4 + r;
                        if (grow < M) {
                            float v = fmaxf(acc[mi][ni][r] + bv, 0.f);
                            atomicAdd(&pooled[batch[grow] * 256 + col], v);
                        }
                    }
                }
            }
        }
    }
}

// ---------------- FFN: relu(pooled/cnt @Wf+bf) @ Wo + bo, one block/graph ----

__global__ __launch_bounds__(256) void ffn_kernel(
    const float* __restrict__ pooled, const int* __restrict__ goff,
    const float* __restrict__ Wf, const float* __restrict__ bf,
    const float* __restrict__ Wo, const float* __restrict__ bo,
    float* __restrict__ out) {
    __shared__ float p[256];
    __shared__ float red[256];
    int g = blockIdx.x, t = threadIdx.x;
    int cnt = goff[g + 1] - goff[g];
    float inv = 1.f / (float)max(cnt, 1);
    p[t] = pooled[g * 256 + t] * inv;
    __syncthreads();
    float s = bf[t];
    #pragma unroll 8
    for (int k = 0; k < 256; ++k) s = fmaf(p[k], Wf[k * 256 + t], s);
    float gv = fmaxf(s, 0.f);
    red[t] = gv * Wo[t];
    __syncthreads();
    for (int o = 128; o > 0; o >>= 1) {
        if (t < o) red[t] += red[t + o];
        __syncthreads();
    }
    if (t == 0) out[g] = red[0] + bo[0];
}

// ---------------------------------------------------------------------------

extern "C" void kernel_launch(void* const* d_in, const int* in_sizes, int n_in,
                              void* d_out, int out_size, void* d_ws, size_t ws_size,
                              hipStream_t stream) {
    const float* x   = (const float*)d_in[0];
    const int*   ei  = (const int*)d_in[1];
    const int*   bat = (const int*)d_in[2];
    const float* W1  = (const float*)d_in[3];
    const float* b1  = (const float*)d_in[4];
    const float* W2  = (const float*)d_in[5];
    const float* b2  = (const float*)d_in[6];
    const float* W3  = (const float*)d_in[7];
    const float* b3  = (const float*)d_in[8];
    const float* Wf  = (const float*)d_in[9];
    const float* bf  = (const float*)d_in[10];
    const float* Wo  = (const float*)d_in[11];
    const float* bo  = (const float*)d_in[12];
    float* out = (float*)d_out;

    const int N  = in_sizes[2];        // 50000
    const int E  = in_sizes[1] / 2;    // 800000
    const int IC = in_sizes[0] / N;    // 128
    const int HID = 256;
    const int G  = out_size;           // 256
    const int Ms = N + 1;              // row stride incl. phantom node
    const int* row = ei;
    const int* col = ei + E;

    char* w = (char*)d_ws;
    size_t off = 0;
    auto alloc = [&](size_t bytes) -> void* {
        void* p = w + off;
        off += (bytes + 255) & ~(size_t)255;
        return p;
    };
    // deg, pooled, bcnt adjacent -> one memset covers all three
    int*   deg    = (int*)alloc((size_t)N * 4);
    float* pooled = (float*)alloc((size_t)G * HID * 4);
    int*   bcnt   = (int*)alloc((size_t)64 * 4);
    float* dis    = (float*)alloc((size_t)N * 4);
    int*   offs   = (int*)alloc((size_t)(N + 1) * 4);
    unsigned short* srcs = (unsigned short*)alloc(((size_t)E + 7 * (size_t)N + 8) * 2);
    unsigned int* bins = (unsigned int*)alloc((size_t)(E + 8) * 4);
    int*   scnt   = (int*)alloc((size_t)8 * 4);
    int*   binoff = (int*)alloc((size_t)9 * 4);
    int*   bcur   = (int*)alloc((size_t)8 * 4);
    int*   goff   = (int*)alloc((size_t)(G + 1) * 4);
    int*   bsum   = (int*)alloc((size_t)64 * 4);
    int*   order  = (int*)alloc((size_t)N * 4);
    _Float16* W1t = (_Float16*)alloc((size_t)HID * IC * 2);
    _Float16* W2t = (_Float16*)alloc((size_t)HID * HID * 2);
    _Float16* W3t = (_Float16*)alloc((size_t)HID * HID * 2);
    _Float16* Xs  = (_Float16*)alloc((size_t)Ms * IC * 2);
    _Float16* Ah  = (_Float16*)alloc((size_t)Ms * HID * 2);
    _Float16* Hs  = (_Float16*)alloc((size_t)Ms * HID * 2);
    (void)ws_size; (void)n_in;

    size_t zlen = (((size_t)N * 4 + 255) & ~(size_t)255)
                + (((size_t)G * HID * 4 + 255) & ~(size_t)255)
                + (size_t)64 * 4;
    hipMemsetAsync(deg, 0, zlen, stream);

    degree_goff_kernel<<<(E + THREADS - 1) / THREADS, THREADS, 0, stream>>>(
        col, deg, E, bat, goff, N, G);

    int nblk = (N + THREADS - 1) / THREADS;
    bucketcnt_kernel<<<nblk, THREADS, 0, stream>>>(deg, bcnt, N);
    bucketscan_kernel<<<1, 64, 0, stream>>>(bcnt);
    place_kernel<<<nblk, THREADS, 0, stream>>>(deg, bcnt, order, N);

    int nb = (N + 1023) / 1024;   // 49 <= 64
    scanA_kernel<<<nb, 256, 0, stream>>>(deg, offs, bsum, dis, N);
    scanB_kernel<<<1, 64, 0, stream>>>(bsum, &offs[N], nb);

    slicecnt_kernel<<<8, 256, 0, stream>>>(deg, scnt, N);
    scan8_kernel<<<1, 64, 0, stream>>>(scnt, binoff, bcur);
    translate_bin_kernel<<<(E + 2047) / 2048, 256, 0, stream>>>(
        row, col, bins, bcur, E, N);

    int total8 = N * IC / 8;
    int conv_total = N + total8 + IC * HID + HID * HID + HID * HID + 8 * (IC / 8) + 256;
    convert_kernel<<<(conv_total + THREADS - 1) / THREADS, THREADS, 0, stream>>>(
        offs, bsum, N, x, dis, Xs, total8, IC, W1, W1t, IC, W2, W2t, W3, W3t, Hs);

    int SL = (N + 7) >> 3;
    int pf_tiles = (SL + THREADS - 1) / THREADS;
    padfill_x_kernel<<<pf_tiles * 8, THREADS, 0, stream>>>(offs, deg, srcs, N);
    int CPS = (E + 8 * 2048 - 1) / (8 * 2048);   // chunks per slice (~49)
    csr_fill2_kernel<<<CPS * 8, 256, 0, stream>>>(bins, binoff, offs, deg, srcs, CPS);

    int mtiles = (N + 63) / 64;   // 782
    // layer 1 (128 ch: 2 lanes/node/slice, 128 nodes/block)
    int nt1 = (N + 127) / 128;
    aggregate_slice_kernel<128><<<nt1 * 8, 256, 0, stream>>>(Xs, offs, srcs, dis, order, Ah, N);
    gemm_as_kernel<128, 1><<<mtiles, 256, 0, stream>>>(Ah, W1t, b1, dis, Hs, nullptr, nullptr, N, Ms);
    // layer 2 (256 ch: 4 lanes/node/slice, 64 nodes/block)
    int nt2 = (N + 63) / 64;
    aggregate_slice_kernel<256><<<nt2 * 8, 256, 0, stream>>>(Hs, offs, srcs, dis, order, Ah, N);
    gemm_as_kernel<256, 1><<<mtiles, 256, 0, stream>>>(Ah, W2t, b2, dis, Hs, nullptr, nullptr, N, Ms);
    // layer 3: GEMM fuses mean-pool (no H write)
    aggregate_slice_kernel<256><<<nt2 * 8, 256, 0, stream>>>(Hs, offs, srcs, dis, order, Ah, N);
    gemm_as_kernel<256, 2><<<mtiles, 256, 0, stream>>>(Ah, W3t, b3, nullptr, nullptr, pooled, bat, N, Ms);

    ffn_kernel<<<G, 256, 0, stream>>>(pooled, goff, Wf, bf, Wo, bo, out);
}

// Round 10
// 427.773 us; speedup vs baseline: 2.7782x; 2.7782x over previous
//
#include <hip/hip_runtime.h>
#include <hip/hip_bf16.h>
#include <hip/hip_fp16.h>

// ---------------------------------------------------------------------------
// GCN forward:  per layer  h' = ReLU( (Â h) @ W + b ),  aggregate-first.
// Node features stored fp16 PRE-SCALED by dis[i]:  hs[i] = dis[i]*h[i]
//   -> aggregation is a pure gather-SUM: a[i] = dis[i]*(hs[i] + sum hs[s])
// R17: 8-way channel slice, SLICE-MAJOR layout, XCD-pinned (bid&7 -> XCD).
//   Per-XCD gather footprint 3.2MB -> L2-resident (FETCH 159->32MB).
// R18: edge lists padded to x8 (phantom node N) + dwordx4 u16 index loads +
//   prefetch + 8-deep gather pipeline.
// R19: XCD-localized CSR scatter (write-merge in one L2).
// R23: edge binning in node space (translate_bin + csr_fill2).
// R24: ORDER-INDIRECTION for divergence-free aggregate waves (node =
//   order[slot], order = counting sort by ceil(deg/8) bucket).
// R25: R24's sort kernels used 50K device-scope atomics on ~4 hot addresses
//   (degrees cluster ~16) -> place_kernel alone 378us (VALUBusy 0.004%).
//   Fix: hierarchical histogram (G12): per-block LDS histogram + block-rank,
//   ONE global atomicAdd per (block,bucket) to reserve a range. Zero
//   per-node global atomics. Everything else identical to R24.
// R15 GEMM: A-STATIONARY, 64-row LDS tile (stride K+40), ONE barrier,
// barrier-free K-loop, B direct from global (L2-hot). Layer-3 fuses pool.
// ---------------------------------------------------------------------------

#define THREADS 256

typedef _Float16 f16x8 __attribute__((ext_vector_type(8)));
typedef float    f32x4 __attribute__((ext_vector_type(4)));
typedef unsigned short u16x8 __attribute__((ext_vector_type(8)));

// ---------------- setup kernels ----------------

// degree histogram (i<E) + graph offsets from sorted batch (i<N), one launch
__global__ void degree_goff_kernel(const int* __restrict__ col, int* __restrict__ deg, int E,
                                   const int* __restrict__ batch, int* __restrict__ goff,
                                   int N, int G) {
    int i = blockIdx.x * THREADS + threadIdx.x;
    if (i < E) atomicAdd(&deg[col[i]], 1);
    if (i < N) {
        int b1 = batch[i];
        int b0 = (i == 0) ? -1 : batch[i - 1];
        for (int g = b0 + 1; g <= b1; ++g) goff[g] = i;
        if (i == N - 1) {
            for (int g = b1 + 1; g <= G; ++g) goff[g] = N;
        }
    }
}

// count nodes per degree bucket (64 buckets of ceil(deg/8)) — hierarchical:
// per-block LDS histogram, then one global atomicAdd per non-empty bucket.
__global__ __launch_bounds__(256) void bucketcnt_kernel(
    const int* __restrict__ deg, int* __restrict__ bcnt, int N) {
    __shared__ int lhist[64];
    int t = threadIdx.x;
    if (t < 64) lhist[t] = 0;
    __syncthreads();
    int i = blockIdx.x * THREADS + t;
    if (i < N) atomicAdd(&lhist[min((deg[i] + 7) >> 3, 63)], 1);
    __syncthreads();
    if (t < 64 && lhist[t] > 0) atomicAdd(&bcnt[t], lhist[t]);
}

// exclusive scan of 64 bucket counts, one wave
__global__ void bucketscan_kernel(int* __restrict__ b) {
    int lane = threadIdx.x;
    int v = b[lane];
    int inc = v;
    #pragma unroll
    for (int d = 1; d < 64; d <<= 1) {
        int t = __shfl_up(inc, d);
        if (lane >= d) inc += t;
    }
    b[lane] = inc - v;   // exclusive
}

// place nodes into degree-ordered list — hierarchical: LDS histogram gives
// block-local rank; ONE global atomicAdd per (block,bucket) reserves a base.
__global__ __launch_bounds__(256) void place_kernel(
    const int* __restrict__ deg, int* __restrict__ bcnt,
    int* __restrict__ order, int N) {
    __shared__ int lhist[64], gbase[64];
    int t = threadIdx.x;
    if (t < 64) lhist[t] = 0;
    __syncthreads();
    int i = blockIdx.x * THREADS + t;
    int bkt = -1, rank = 0;
    if (i < N) {
        bkt = min((deg[i] + 7) >> 3, 63);
        rank = atomicAdd(&lhist[bkt], 1);
    }
    __syncthreads();
    if (t < 64 && lhist[t] > 0) gbase[t] = atomicAdd(&bcnt[t], lhist[t]);
    __syncthreads();
    if (i < N) order[gbase[bkt] + rank] = i;
}

// scan phase A: per-block (1024 elems) exclusive scan of PADDED degrees
// (pad to multiple of 8) + block sum; also dis from REAL degree.
__global__ __launch_bounds__(256) void scanA_kernel(
    const int* __restrict__ in, int* __restrict__ out, int* __restrict__ bsum,
    float* __restrict__ dis, int n) {
    __shared__ int wsum[4];
    int i0 = blockIdx.x * 1024 + threadIdx.x * 4;
    int lane = threadIdx.x & 63, wid = threadIdx.x >> 6;
    int v0 = 0, v1 = 0, v2 = 0, v3 = 0;
    if (i0 + 3 < n) {
        int4 v = *(const int4*)&in[i0];
        v0 = v.x; v1 = v.y; v2 = v.z; v3 = v.w;
    } else {
        if (i0 + 0 < n) v0 = in[i0 + 0];
        if (i0 + 1 < n) v1 = in[i0 + 1];
        if (i0 + 2 < n) v2 = in[i0 + 2];
        if (i0 + 3 < n) v3 = in[i0 + 3];
    }
    // dis = rsqrt(deg+1) from real degree
    if (i0 + 0 < n) dis[i0 + 0] = rsqrtf((float)(v0 + 1));
    if (i0 + 1 < n) dis[i0 + 1] = rsqrtf((float)(v1 + 1));
    if (i0 + 2 < n) dis[i0 + 2] = rsqrtf((float)(v2 + 1));
    if (i0 + 3 < n) dis[i0 + 3] = rsqrtf((float)(v3 + 1));
    // pad degrees to multiple of 8 for the scan
    v0 = (v0 + 7) & ~7; v1 = (v1 + 7) & ~7;
    v2 = (v2 + 7) & ~7; v3 = (v3 + 7) & ~7;
    int s = v0 + v1 + v2 + v3;
    int inc = s;
    #pragma unroll
    for (int d = 1; d < 64; d <<= 1) {
        int t = __shfl_up(inc, d);
        if (lane >= d) inc += t;
    }
    if (lane == 63) wsum[wid] = inc;
    __syncthreads();
    int add = 0;
    for (int w = 0; w < wid; ++w) add += wsum[w];
    int ex = add + inc - s;
    if (i0 + 0 < n) out[i0 + 0] = ex;
    if (i0 + 1 < n) out[i0 + 1] = ex + v0;
    if (i0 + 2 < n) out[i0 + 2] = ex + v0 + v1;
    if (i0 + 3 < n) out[i0 + 3] = ex + v0 + v1 + v2;
    if (threadIdx.x == 255) bsum[blockIdx.x] = add + inc;  // block total
}

// scan phase B: 1 wave scans <=64 block sums; writes grand total to out[n].
__global__ void scanB_kernel(int* __restrict__ bsum, int* __restrict__ total_slot, int nb) {
    int lane = threadIdx.x;
    int v = (lane < nb) ? bsum[lane] : 0;
    int inc = v;
    #pragma unroll
    for (int d = 1; d < 64; d <<= 1) {
        int t = __shfl_up(inc, d);
        if (lane >= d) inc += t;
    }
    if (lane < nb) bsum[lane] = inc - v;   // exclusive
    if (lane == 63) *total_slot = inc;
}

// per-slice REAL edge counts: 8 blocks; block s sums deg over its node range
__global__ __launch_bounds__(256) void slicecnt_kernel(
    const int* __restrict__ deg, int* __restrict__ scnt, int N) {
    __shared__ int wsum[4];
    int s = blockIdx.x;
    int SL = (N + 7) >> 3;
    int lo = s * SL, hi = min(N, lo + SL);
    int acc = 0;
    for (int i = lo + (int)threadIdx.x; i < hi; i += 256) acc += deg[i];
    #pragma unroll
    for (int d = 1; d < 64; d <<= 1) acc += __shfl_xor(acc, d);
    int lane = threadIdx.x & 63, wid = threadIdx.x >> 6;
    if (lane == 0) wsum[wid] = acc;
    __syncthreads();
    if (threadIdx.x == 0) scnt[s] = wsum[0] + wsum[1] + wsum[2] + wsum[3];
}

// scan 8 slice counts -> binoff[0..8], init bcur
__global__ void scan8_kernel(const int* __restrict__ scnt, int* __restrict__ binoff,
                             int* __restrict__ bcur) {
    if (threadIdx.x == 0 && blockIdx.x == 0) {
        int cum = 0;
        for (int s = 0; s < 8; ++s) { binoff[s] = cum; bcur[s] = cum; cum += scnt[s]; }
        binoff[8] = cum;
    }
}

// LDS-partition edges into 8 per-slice bins (u32 = col | row<<16, N<65536).
// One pass over int edges (read ONCE); dense ~1KB bulk appends per bin.
__global__ __launch_bounds__(256) void translate_bin_kernel(
    const int* __restrict__ row, const int* __restrict__ col,
    unsigned int* __restrict__ bins, int* __restrict__ bcur, int E, int N) {
    __shared__ unsigned int lent[2048];
    __shared__ int lhist[8], lbase[8], gbase[8], lpos[8];
    int t = threadIdx.x;
    if (t < 8) lhist[t] = 0;
    __syncthreads();
    int SL = (N + 7) >> 3;
    int e0 = blockIdx.x * 2048 + t * 8;
    unsigned int ent[8]; int sl[8];
    int n = E - e0; if (n < 0) n = 0; if (n > 8) n = 8;
    if (n == 8) {
        int4 c0 = *(const int4*)&col[e0];
        int4 c1 = *(const int4*)&col[e0 + 4];
        int4 r0 = *(const int4*)&row[e0];
        int4 r1 = *(const int4*)&row[e0 + 4];
        int cs[8] = {c0.x, c0.y, c0.z, c0.w, c1.x, c1.y, c1.z, c1.w};
        int rs[8] = {r0.x, r0.y, r0.z, r0.w, r1.x, r1.y, r1.z, r1.w};
        #pragma unroll
        for (int j = 0; j < 8; ++j) {
            sl[j] = cs[j] / SL;
            ent[j] = (unsigned int)cs[j] | ((unsigned int)rs[j] << 16);
            atomicAdd(&lhist[sl[j]], 1);
        }
    } else {
        for (int j = 0; j < n; ++j) {
            int c = col[e0 + j], r = row[e0 + j];
            sl[j] = c / SL;
            ent[j] = (unsigned int)c | ((unsigned int)r << 16);
            atomicAdd(&lhist[sl[j]], 1);
        }
    }
    __syncthreads();
    if (t == 0) {
        int cum = 0;
        #pragma unroll
        for (int s = 0; s < 8; ++s) { lbase[s] = cum; cum += lhist[s]; }
    }
    __syncthreads();
    if (t < 8) { gbase[t] = atomicAdd(&bcur[t], lhist[t]); lpos[t] = lbase[t]; }
    __syncthreads();
    for (int j = 0; j < n; ++j) {
        int p = atomicAdd(&lpos[sl[j]], 1);
        lent[p] = ent[j];
    }
    __syncthreads();
    int total = lbase[7] + lhist[7];
    for (int k = t; k < total; k += 256) {
        unsigned int e = lent[k];
        int s = 0;
        #pragma unroll
        for (int b = 1; b < 8; ++b) s = (k >= lbase[b]) ? b : s;
        bins[gbase[s] + (k - lbase[s])] = e;
    }
}

// fill phantom pad slots [offs[c]+deg[c], offs[c+1]) with node id N.
// XCD-localized; runs after convert (offs final), before csr_fill2 (deg intact).
__global__ __launch_bounds__(256) void padfill_x_kernel(
    const int* __restrict__ offs, const int* __restrict__ deg,
    unsigned short* __restrict__ srcs, int N) {
    int slice = blockIdx.x & 7;
    int SL = (N + 7) >> 3;
    int node = slice * SL + (int)(blockIdx.x >> 3) * THREADS + threadIdx.x;
    int nhi = min(N, slice * SL + SL);
    if (node >= nhi) return;
    int s = offs[node] + deg[node], e = offs[node + 1];
    for (int i = s; i < e; ++i) srcs[i] = (unsigned short)N;
}

// CSR scatter phase 2: block bid&7 = slice = XCD; streams ONLY its slice's
// bin (dense u32, no duplication), scatters into its L2-resident srcs slice
// -> full-line write merge. Grid-stride handles skew. deg is the countdown.
__global__ __launch_bounds__(256) void csr_fill2_kernel(
    const unsigned int* __restrict__ bins, const int* __restrict__ binoff,
    const int* __restrict__ offs, int* __restrict__ deg,
    unsigned short* __restrict__ srcs, int CPS) {
    int slice = blockIdx.x & 7;
    int chunk = blockIdx.x >> 3;
    int lo = binoff[slice], hi = binoff[slice + 1];
    for (int base = lo + chunk * 2048; base < hi; base += CPS * 2048) {
        int i0 = base + (int)threadIdx.x * 8;
        #pragma unroll
        for (int j = 0; j < 8; ++j) {
            int i = i0 + j;
            if (i < hi) {
                unsigned int e = bins[i];
                int c = (int)(e & 0xffffu);
                int r = (int)(e >> 16);
                int old = atomicSub(&deg[c], 1);
                srcs[offs[c] + old - 1] = (unsigned short)r;
            }
        }
    }
}

// merged: scanC (offs += bsum) + x fp32->fp16*dis (slice-major, stride N+1)
// + W1/W2/W3 -> fp16^T + phantom-row zeroing for Xs and Hs.
__global__ void convert_kernel(
    int* __restrict__ offs, const int* __restrict__ bsum, int Nfix,
    const float* __restrict__ X, const float* __restrict__ dis,
    _Float16* __restrict__ Xs, int total8, int IC,
    const float* __restrict__ W1, _Float16* __restrict__ W1t, int k1,   // k1=IC
    const float* __restrict__ W2, _Float16* __restrict__ W2t,
    const float* __restrict__ W3, _Float16* __restrict__ W3t,
    _Float16* __restrict__ Hs) {
    int i = blockIdx.x * THREADS + threadIdx.x;
    if (i < Nfix) {                         // scanC: add scanned block offsets
        offs[i] += bsum[i >> 10];
        return;
    }
    int j = i - Nfix;
    int Ms = Nfix + 1;                      // row stride incl. phantom
    if (j < total8) {
        int idx = j * 8;
        int node = idx / IC;
        int ch0  = idx % IC;
        float d = dis[node];
        float4 a = *(const float4*)&X[idx];
        float4 b = *(const float4*)&X[idx + 4];
        f16x8 o;
        o[0] = (_Float16)(d * a.x); o[1] = (_Float16)(d * a.y);
        o[2] = (_Float16)(d * a.z); o[3] = (_Float16)(d * a.w);
        o[4] = (_Float16)(d * b.x); o[5] = (_Float16)(d * b.y);
        o[6] = (_Float16)(d * b.z); o[7] = (_Float16)(d * b.w);
        int sw = IC >> 3;                   // slice width in f16 (IC=128 -> 16)
        int slice = ch0 / sw, within = ch0 % sw;
        *(f16x8*)&Xs[((size_t)slice * Ms + node) * sw + within] = o;
        return;
    }
    j -= total8;
    int n1 = k1 * 256;
    if (j < n1) {                 // W1 [k1 x 256] -> W1t [256 x k1]
        int k = j >> 8, n = j & 255;
        W1t[n * k1 + k] = (_Float16)W1[j];
        return;
    }
    j -= n1;
    if (j < 65536) {              // W2 [256 x 256]
        int k = j >> 8, n = j & 255;
        W2t[n * 256 + k] = (_Float16)W2[j];
        return;
    }
    j -= 65536;
    if (j < 65536) {              // W3
        int k = j >> 8, n = j & 255;
        W3t[n * 256 + k] = (_Float16)W3[j];
        return;
    }
    j -= 65536;
    {   // zero phantom rows: Xs 8 slices x (IC/8) f16, Hs 8 slices x 32 f16
        int swx = IC >> 3;
        int nx = 8 * swx;
        if (j < nx) {
            int slice = j / swx, wi = j % swx;
            Xs[((size_t)slice * Ms + Nfix) * swx + wi] = (_Float16)0.f;
            return;
        }
        j -= nx;
        if (j < 256) {
            int slice = j >> 5, wi = j & 31;
            Hs[((size_t)slice * Ms + Nfix) * 32 + wi] = (_Float16)0.f;
        }
    }
}

// ---- aggregation: a[i] = dis[i] * ( hs[i] + sum_{s in nbr} hs[s] ) ----------
// 8-way slice-major, XCD-pinned (bid&7 = slice = XCD; slice L2-resident).
// R24: node = order[slot] (degree-ordered) -> waves hold nodes of identical
// trip-count bucket -> no intra-wave divergence. Padded edge lists (x8,
// phantom node N): indices load as one dwordx4 (8 x u16), prefetched one
// iteration ahead; 8 gathers in flight. fp32 accumulate. Output writes are
// scattered 64B granules inside this XCD's own L2-resident slice (normal
// stores so they merge in L2).

template<int CH>   // full channel count: 128 or 256
__global__ __launch_bounds__(256) void aggregate_slice_kernel(
    const _Float16* __restrict__ X, const int* __restrict__ offs,
    const unsigned short* __restrict__ srcs, const float* __restrict__ dis,
    const int* __restrict__ order, _Float16* __restrict__ A, int N) {
    constexpr int LPN = CH / 64;          // f16x8 lanes per node per slice (2 / 4)
    constexpr int NPB = 256 / LPN;        // nodes per block (128 / 64)
    int bid   = blockIdx.x;
    int slice = bid & 7;                  // round-robin -> XCD id
    int tile  = bid >> 3;
    int slot  = tile * NPB + threadIdx.x / LPN;
    if (slot >= N) return;
    int node = order[slot];               // degree-ordered (broadcast read)
    int lane = threadIdx.x % LPN;
    size_t Ms = (size_t)N + 1;            // row stride incl. phantom
    const f16x8* Xv = (const f16x8*)X + (size_t)slice * Ms * LPN;
    f16x8 self = Xv[(size_t)node * LPN + lane];
    float acc[8], acc2[8];
    #pragma unroll
    for (int j = 0; j < 8; ++j) { acc[j] = (float)self[j]; acc2[j] = 0.f; }
    int s = offs[node], e = offs[node + 1];
    int nit = (e - s) >> 3;               // padded: always a multiple of 8
    if (nit > 0) {
        const u16x8* ip = (const u16x8*)&srcs[s];   // 16B-aligned (s % 8 == 0)
        u16x8 idx = ip[0];
        for (int it = 0; it < nit; ++it) {
            u16x8 nxt = ip[min(it + 1, nit - 1)];   // prefetch next 8 indices
            f16x8 v0 = Xv[(size_t)idx[0] * LPN + lane];
            f16x8 v1 = Xv[(size_t)idx[1] * LPN + lane];
            f16x8 v2 = Xv[(size_t)idx[2] * LPN + lane];
            f16x8 v3 = Xv[(size_t)idx[3] * LPN + lane];
            f16x8 v4 = Xv[(size_t)idx[4] * LPN + lane];
            f16x8 v5 = Xv[(size_t)idx[5] * LPN + lane];
            f16x8 v6 = Xv[(size_t)idx[6] * LPN + lane];
            f16x8 v7 = Xv[(size_t)idx[7] * LPN + lane];
            #pragma unroll
            for (int j = 0; j < 8; ++j) {
                acc[j]  += ((float)v0[j] + (float)v2[j]) + ((float)v4[j] + (float)v6[j]);
                acc2[j] += ((float)v1[j] + (float)v3[j]) + ((float)v5[j] + (float)v7[j]);
            }
            idx = nxt;
        }
    }
    float dn = dis[node];
    f16x8 o;
    #pragma unroll
    for (int j = 0; j < 8; ++j) o[j] = (_Float16)(dn * (acc[j] + acc2[j]));
    f16x8* Av = (f16x8*)A + (size_t)slice * Ms * LPN;
    Av[(size_t)node * LPN + lane] = o;
}

// ---- A-STATIONARY GEMM: H[m,:256] = relu( A[m,:K] @ W^T + bias ) -----------
// A is slice-major [8][Ms][K/8] (Ms = N+1 incl. phantom). Staged into LDS as
// row-major [64][K] (k = seg*8 identity), MFMA loop unchanged. 64-row tile,
// stride K+40, ONE barrier, barrier-free K-loop, B direct from global.
// MODE 1: write H (slice-major, dscaled). MODE 2: fused mean-pool epilogue.

template<int K, int MODE>
__global__ __launch_bounds__(256) void gemm_as_kernel(
    const _Float16* __restrict__ A, const _Float16* __restrict__ Bt,
    const float* __restrict__ bias, const float* __restrict__ dscale,
    _Float16* __restrict__ H, float* __restrict__ pooled,
    const int* __restrict__ batch, int M, int Ms) {
    constexpr int LSA = K + 40;               // ≡ 40 mod 64 -> even bank spread
    constexpr int KC = K / 32;
    constexpr int SPR = K / 8;                // 16B segs per row
    constexpr int SPS = K / 64;               // segs per slice (2 / 4)
    constexpr int SW  = K / 8;                // f16 per slice (16 / 32)
    __shared__ _Float16 As[64 * LSA];
    int tid = threadIdx.x;
    int m0 = blockIdx.x * 64;

    // stage A tile once (slice-major source; contiguous 64B runs per slice)
    {
        constexpr int RPI = 256 / SPR;        // 8 rows/iter (K=256), 16 (K=128)
        int r_in = tid % RPI;                 // consecutive lanes -> distinct rows
        int seg  = tid / RPI;
        int slice = seg / SPS, sub = seg % SPS;
        #pragma unroll
        for (int it = 0; it < 64 / RPI; ++it) {
            int r = it * RPI + r_in;
            int gr = m0 + r;
            uint4 v = make_uint4(0, 0, 0, 0);
            if (gr < M) v = *(const uint4*)&A[((size_t)slice * Ms + gr) * SW + sub * 8];
            *(uint4*)&As[r * LSA + seg * 8] = v;
        }
    }
    __syncthreads();

    int wid = tid >> 6, lane = tid & 63;
    int l16 = lane & 15, quad = lane >> 4;
    int wn = wid * 64;                        // this wave's 64 output cols

    f32x4 acc[4][4] = {};
    const _Float16* Bbase = Bt + (size_t)(wn + l16) * K + quad * 8;

    #pragma unroll
    for (int kc = 0; kc < KC; ++kc) {
        f16x8 bh[4];
        #pragma unroll
        for (int ni = 0; ni < 4; ++ni)
            bh[ni] = *(const f16x8*)&Bbase[(size_t)(ni * 16) * K + kc * 32];
        #pragma unroll
        for (int mi = 0; mi < 4; ++mi) {
            f16x8 ah = *(const f16x8*)&As[(mi * 16 + l16) * LSA + kc * 32 + quad * 8];
            #pragma unroll
            for (int ni = 0; ni < 4; ++ni)
                acc[mi][ni] = __builtin_amdgcn_mfma_f32_16x16x32_f16(ah, bh[ni], acc[mi][ni], 0, 0, 0);
        }
    }

    #pragma unroll
    for (int mi = 0; mi < 4; ++mi) {
        int rbase = m0 + mi * 16;
        int g0 = 0, g15 = 0;
        if (MODE == 2) {
            g0  = batch[min(rbase, M - 1)];
            g15 = batch[min(rbase + 15, M - 1)];
        }
        #pragma unroll
        for (int ni = 0; ni < 4; ++ni) {
            int col = wn + ni * 16 + l16;
            float bv = bias[col];
            if (MODE == 1) {
                // slice-major H: slice = col>>5 (256 cols, 32 f16/slice)
                size_t hbase = (size_t)(col >> 5) * Ms * 32 + (col & 31);
                #pragma unroll
                for (int r = 0; r < 4; ++r) {
                    int grow = rbase + quad * 4 + r;
                    if (grow < M) {
                        float v = fmaxf(acc[mi][ni][r] + bv, 0.f) * dscale[grow];
                        H[hbase + (size_t)grow * 32] = (_Float16)v;
                    }
                }
            } else {  // MODE == 2: fused mean-pool accumulation
                if (g0 == g15) {
                    float p = 0.f;
                    #pragma unroll
                    for (int r = 0; r < 4; ++r) {
                        int grow = rbase + quad * 4 + r;
                        float v = fmaxf(acc[mi][ni][r] + bv, 0.f);
                        p += (grow < M) ? v : 0.f;
                    }
                    p += __shfl_xor(p, 16);
                    p += __shfl_xor(p, 32);
                    if (quad == 0) atomicAdd(&pooled[g0 * 256 + col], p);
                } else {
                    #pragma unroll
                    for (int r = 0; r < 4; ++r) {
                        int grow = rbase + quad * 4 + r;
                        if (grow < M) {
                            float v = fmaxf(acc[mi][ni][r] + bv, 0.f);
                            atomicAdd(&pooled[batch[grow] * 256 + col], v);
                        }
                    }
                }
            }
        }
    }
}

// ---------------- FFN: relu(pooled/cnt @Wf+bf) @ Wo + bo, one block/graph ----

__global__ __launch_bounds__(256) void ffn_kernel(
    const float* __restrict__ pooled, const int* __restrict__ goff,
    const float* __restrict__ Wf, const float* __restrict__ bf,
    const float* __restrict__ Wo, const float* __restrict__ bo,
    float* __restrict__ out) {
    __shared__ float p[256];
    __shared__ float red[256];
    int g = blockIdx.x, t = threadIdx.x;
    int cnt = goff[g + 1] - goff[g];
    float inv = 1.f / (float)max(cnt, 1);
    p[t] = pooled[g * 256 + t] * inv;
    __syncthreads();
    float s = bf[t];
    #pragma unroll 8
    for (int k = 0; k < 256; ++k) s = fmaf(p[k], Wf[k * 256 + t], s);
    float gv = fmaxf(s, 0.f);
    red[t] = gv * Wo[t];
    __syncthreads();
    for (int o = 128; o > 0; o >>= 1) {
        if (t < o) red[t] += red[t + o];
        __syncthreads();
    }
    if (t == 0) out[g] = red[0] + bo[0];
}

// ---------------------------------------------------------------------------

extern "C" void kernel_launch(void* const* d_in, const int* in_sizes, int n_in,
                              void* d_out, int out_size, void* d_ws, size_t ws_size,
                              hipStream_t stream) {
    const float* x   = (const float*)d_in[0];
    const int*   ei  = (const int*)d_in[1];
    const int*   bat = (const int*)d_in[2];
    const float* W1  = (const float*)d_in[3];
    const float* b1  = (const float*)d_in[4];
    const float* W2  = (const float*)d_in[5];
    const float* b2  = (const float*)d_in[6];
    const float* W3  = (const float*)d_in[7];
    const float* b3  = (const float*)d_in[8];
    const float* Wf  = (const float*)d_in[9];
    const float* bf  = (const float*)d_in[10];
    const float* Wo  = (const float*)d_in[11];
    const float* bo  = (const float*)d_in[12];
    float* out = (float*)d_out;

    const int N  = in_sizes[2];        // 50000
    const int E  = in_sizes[1] / 2;    // 800000
    const int IC = in_sizes[0] / N;    // 128
    const int HID = 256;
    const int G  = out_size;           // 256
    const int Ms = N + 1;              // row stride incl. phantom node
    const int* row = ei;
    const int* col = ei + E;

    char* w = (char*)d_ws;
    size_t off = 0;
    auto alloc = [&](size_t bytes) -> void* {
        void* p = w + off;
        off += (bytes + 255) & ~(size_t)255;
        return p;
    };
    // deg, pooled, bcnt adjacent -> one memset covers all three
    int*   deg    = (int*)alloc((size_t)N * 4);
    float* pooled = (float*)alloc((size_t)G * HID * 4);
    int*   bcnt   = (int*)alloc((size_t)64 * 4);
    float* dis    = (float*)alloc((size_t)N * 4);
    int*   offs   = (int*)alloc((size_t)(N + 1) * 4);
    unsigned short* srcs = (unsigned short*)alloc(((size_t)E + 7 * (size_t)N + 8) * 2);
    unsigned int* bins = (unsigned int*)alloc((size_t)(E + 8) * 4);
    int*   scnt   = (int*)alloc((size_t)8 * 4);
    int*   binoff = (int*)alloc((size_t)9 * 4);
    int*   bcur   = (int*)alloc((size_t)8 * 4);
    int*   goff   = (int*)alloc((size_t)(G + 1) * 4);
    int*   bsum   = (int*)alloc((size_t)64 * 4);
    int*   order  = (int*)alloc((size_t)N * 4);
    _Float16* W1t = (_Float16*)alloc((size_t)HID * IC * 2);
    _Float16* W2t = (_Float16*)alloc((size_t)HID * HID * 2);
    _Float16* W3t = (_Float16*)alloc((size_t)HID * HID * 2);
    _Float16* Xs  = (_Float16*)alloc((size_t)Ms * IC * 2);
    _Float16* Ah  = (_Float16*)alloc((size_t)Ms * HID * 2);
    _Float16* Hs  = (_Float16*)alloc((size_t)Ms * HID * 2);
    (void)ws_size; (void)n_in;

    size_t zlen = (((size_t)N * 4 + 255) & ~(size_t)255)
                + (((size_t)G * HID * 4 + 255) & ~(size_t)255)
                + (size_t)64 * 4;
    hipMemsetAsync(deg, 0, zlen, stream);

    degree_goff_kernel<<<(E + THREADS - 1) / THREADS, THREADS, 0, stream>>>(
        col, deg, E, bat, goff, N, G);

    int nblk = (N + THREADS - 1) / THREADS;
    bucketcnt_kernel<<<nblk, THREADS, 0, stream>>>(deg, bcnt, N);
    bucketscan_kernel<<<1, 64, 0, stream>>>(bcnt);
    place_kernel<<<nblk, THREADS, 0, stream>>>(deg, bcnt, order, N);

    int nb = (N + 1023) / 1024;   // 49 <= 64
    scanA_kernel<<<nb, 256, 0, stream>>>(deg, offs, bsum, dis, N);
    scanB_kernel<<<1, 64, 0, stream>>>(bsum, &offs[N], nb);

    slicecnt_kernel<<<8, 256, 0, stream>>>(deg, scnt, N);
    scan8_kernel<<<1, 64, 0, stream>>>(scnt, binoff, bcur);
    translate_bin_kernel<<<(E + 2047) / 2048, 256, 0, stream>>>(
        row, col, bins, bcur, E, N);

    int total8 = N * IC / 8;
    int conv_total = N + total8 + IC * HID + HID * HID + HID * HID + 8 * (IC / 8) + 256;
    convert_kernel<<<(conv_total + THREADS - 1) / THREADS, THREADS, 0, stream>>>(
        offs, bsum, N, x, dis, Xs, total8, IC, W1, W1t, IC, W2, W2t, W3, W3t, Hs);

    int SL = (N + 7) >> 3;
    int pf_tiles = (SL + THREADS - 1) / THREADS;
    padfill_x_kernel<<<pf_tiles * 8, THREADS, 0, stream>>>(offs, deg, srcs, N);
    int CPS = (E + 8 * 2048 - 1) / (8 * 2048);   // chunks per slice (~49)
    csr_fill2_kernel<<<CPS * 8, 256, 0, stream>>>(bins, binoff, offs, deg, srcs, CPS);

    int mtiles = (N + 63) / 64;   // 782
    // layer 1 (128 ch: 2 lanes/node/slice, 128 nodes/block)
    int nt1 = (N + 127) / 128;
    aggregate_slice_kernel<128><<<nt1 * 8, 256, 0, stream>>>(Xs, offs, srcs, dis, order, Ah, N);
    gemm_as_kernel<128, 1><<<mtiles, 256, 0, stream>>>(Ah, W1t, b1, dis, Hs, nullptr, nullptr, N, Ms);
    // layer 2 (256 ch: 4 lanes/node/slice, 64 nodes/block)
    int nt2 = (N + 63) / 64;
    aggregate_slice_kernel<256><<<nt2 * 8, 256, 0, stream>>>(Hs, offs, srcs, dis, order, Ah, N);
    gemm_as_kernel<256, 1><<<mtiles, 256, 0, stream>>>(Ah, W2t, b2, dis, Hs, nullptr, nullptr, N, Ms);
    // layer 3: GEMM fuses mean-pool (no H write)
    aggregate_slice_kernel<256><<<nt2 * 8, 256, 0, stream>>>(Hs, offs, srcs, dis, order, Ah, N);
    gemm_as_kernel<256, 2><<<mtiles, 256, 0, stream>>>(Ah, W3t, b3, nullptr, nullptr, pooled, bat, N, Ms);

    ffn_kernel<<<G, 256, 0, stream>>>(pooled, goff, Wf, bf, Wo, bo, out);
}

// Round 11
// 406.958 us; speedup vs baseline: 2.9203x; 1.0511x over previous
//
#include <hip/hip_runtime.h>
#include <hip/hip_bf16.h>
#include <hip/hip_fp16.h>

// ---------------------------------------------------------------------------
// GCN forward:  per layer  h' = ReLU( (Â h) @ W + b ),  aggregate-first.
// Node features stored fp16 PRE-SCALED by dis[i]:  hs[i] = dis[i]*h[i]
//   -> aggregation is a pure gather-SUM: a[i] = dis[i]*(hs[i] + sum hs[s])
// R17: 8-way channel slice, SLICE-MAJOR layout, XCD-pinned (bid&7 -> XCD).
//   Per-XCD gather footprint 3.2MB -> L2-resident (FETCH 159->32MB).
// R18: edge lists padded to x8 (phantom node N) + dwordx4 u16 index loads +
//   prefetch + 8-deep gather pipeline.
// R19: XCD-localized CSR scatter (write-merge in one L2).
// R23: edge binning in node space (translate_bin + csr_fill2).
// R24/R25 post-mortem (REVERTED): order-indirection removed divergence
//   (VALUBusy 43->30%) but scattered A-writes caused RMW-fetch (+33MB,
//   +4.5us). Dense writes beat divergence-free waves; node = slot restored.
// R26: aggregate is issue/latency bound (43% VALU, nothing saturated).
//   Cut VALU/iter ~30%: ONE-LEVEL f16 PAIRWISE ADD (v_pk_add_f16, 2ch/op)
//   before f32 conversion — 16 pk + 32 cvt + 32 add vs 64 cvt + 48 add.
//   Precision: +1 f16 rounding on top of storage quant (absmax ~2x, passes).
// R15 GEMM: A-STATIONARY, 64-row LDS tile (stride K+40), ONE barrier,
// barrier-free K-loop, B direct from global (L2-hot). Layer-3 fuses pool.
// ---------------------------------------------------------------------------

#define THREADS 256

typedef _Float16 f16x8 __attribute__((ext_vector_type(8)));
typedef float    f32x4 __attribute__((ext_vector_type(4)));
typedef unsigned short u16x8 __attribute__((ext_vector_type(8)));

// ---------------- setup kernels ----------------

// degree histogram (i<E) + graph offsets from sorted batch (i<N), one launch
__global__ void degree_goff_kernel(const int* __restrict__ col, int* __restrict__ deg, int E,
                                   const int* __restrict__ batch, int* __restrict__ goff,
                                   int N, int G) {
    int i = blockIdx.x * THREADS + threadIdx.x;
    if (i < E) atomicAdd(&deg[col[i]], 1);
    if (i < N) {
        int b1 = batch[i];
        int b0 = (i == 0) ? -1 : batch[i - 1];
        for (int g = b0 + 1; g <= b1; ++g) goff[g] = i;
        if (i == N - 1) {
            for (int g = b1 + 1; g <= G; ++g) goff[g] = N;
        }
    }
}

// scan phase A: per-block (1024 elems) exclusive scan of PADDED degrees
// (pad to multiple of 8) + block sum; also dis from REAL degree.
__global__ __launch_bounds__(256) void scanA_kernel(
    const int* __restrict__ in, int* __restrict__ out, int* __restrict__ bsum,
    float* __restrict__ dis, int n) {
    __shared__ int wsum[4];
    int i0 = blockIdx.x * 1024 + threadIdx.x * 4;
    int lane = threadIdx.x & 63, wid = threadIdx.x >> 6;
    int v0 = 0, v1 = 0, v2 = 0, v3 = 0;
    if (i0 + 3 < n) {
        int4 v = *(const int4*)&in[i0];
        v0 = v.x; v1 = v.y; v2 = v.z; v3 = v.w;
    } else {
        if (i0 + 0 < n) v0 = in[i0 + 0];
        if (i0 + 1 < n) v1 = in[i0 + 1];
        if (i0 + 2 < n) v2 = in[i0 + 2];
        if (i0 + 3 < n) v3 = in[i0 + 3];
    }
    // dis = rsqrt(deg+1) from real degree
    if (i0 + 0 < n) dis[i0 + 0] = rsqrtf((float)(v0 + 1));
    if (i0 + 1 < n) dis[i0 + 1] = rsqrtf((float)(v1 + 1));
    if (i0 + 2 < n) dis[i0 + 2] = rsqrtf((float)(v2 + 1));
    if (i0 + 3 < n) dis[i0 + 3] = rsqrtf((float)(v3 + 1));
    // pad degrees to multiple of 8 for the scan
    v0 = (v0 + 7) & ~7; v1 = (v1 + 7) & ~7;
    v2 = (v2 + 7) & ~7; v3 = (v3 + 7) & ~7;
    int s = v0 + v1 + v2 + v3;
    int inc = s;
    #pragma unroll
    for (int d = 1; d < 64; d <<= 1) {
        int t = __shfl_up(inc, d);
        if (lane >= d) inc += t;
    }
    if (lane == 63) wsum[wid] = inc;
    __syncthreads();
    int add = 0;
    for (int w = 0; w < wid; ++w) add += wsum[w];
    int ex = add + inc - s;
    if (i0 + 0 < n) out[i0 + 0] = ex;
    if (i0 + 1 < n) out[i0 + 1] = ex + v0;
    if (i0 + 2 < n) out[i0 + 2] = ex + v0 + v1;
    if (i0 + 3 < n) out[i0 + 3] = ex + v0 + v1 + v2;
    if (threadIdx.x == 255) bsum[blockIdx.x] = add + inc;  // block total
}

// scan phase B: 1 wave scans <=64 block sums; writes grand total to out[n].
__global__ void scanB_kernel(int* __restrict__ bsum, int* __restrict__ total_slot, int nb) {
    int lane = threadIdx.x;
    int v = (lane < nb) ? bsum[lane] : 0;
    int inc = v;
    #pragma unroll
    for (int d = 1; d < 64; d <<= 1) {
        int t = __shfl_up(inc, d);
        if (lane >= d) inc += t;
    }
    if (lane < nb) bsum[lane] = inc - v;   // exclusive
    if (lane == 63) *total_slot = inc;
}

// per-slice REAL edge counts: 8 blocks; block s sums deg over its node range
__global__ __launch_bounds__(256) void slicecnt_kernel(
    const int* __restrict__ deg, int* __restrict__ scnt, int N) {
    __shared__ int wsum[4];
    int s = blockIdx.x;
    int SL = (N + 7) >> 3;
    int lo = s * SL, hi = min(N, lo + SL);
    int acc = 0;
    for (int i = lo + (int)threadIdx.x; i < hi; i += 256) acc += deg[i];
    #pragma unroll
    for (int d = 1; d < 64; d <<= 1) acc += __shfl_xor(acc, d);
    int lane = threadIdx.x & 63, wid = threadIdx.x >> 6;
    if (lane == 0) wsum[wid] = acc;
    __syncthreads();
    if (threadIdx.x == 0) scnt[s] = wsum[0] + wsum[1] + wsum[2] + wsum[3];
}

// scan 8 slice counts -> binoff[0..8], init bcur
__global__ void scan8_kernel(const int* __restrict__ scnt, int* __restrict__ binoff,
                             int* __restrict__ bcur) {
    if (threadIdx.x == 0 && blockIdx.x == 0) {
        int cum = 0;
        for (int s = 0; s < 8; ++s) { binoff[s] = cum; bcur[s] = cum; cum += scnt[s]; }
        binoff[8] = cum;
    }
}

// LDS-partition edges into 8 per-slice bins (u32 = col | row<<16, N<65536).
// One pass over int edges (read ONCE); dense ~1KB bulk appends per bin.
__global__ __launch_bounds__(256) void translate_bin_kernel(
    const int* __restrict__ row, const int* __restrict__ col,
    unsigned int* __restrict__ bins, int* __restrict__ bcur, int E, int N) {
    __shared__ unsigned int lent[2048];
    __shared__ int lhist[8], lbase[8], gbase[8], lpos[8];
    int t = threadIdx.x;
    if (t < 8) lhist[t] = 0;
    __syncthreads();
    int SL = (N + 7) >> 3;
    int e0 = blockIdx.x * 2048 + t * 8;
    unsigned int ent[8]; int sl[8];
    int n = E - e0; if (n < 0) n = 0; if (n > 8) n = 8;
    if (n == 8) {
        int4 c0 = *(const int4*)&col[e0];
        int4 c1 = *(const int4*)&col[e0 + 4];
        int4 r0 = *(const int4*)&row[e0];
        int4 r1 = *(const int4*)&row[e0 + 4];
        int cs[8] = {c0.x, c0.y, c0.z, c0.w, c1.x, c1.y, c1.z, c1.w};
        int rs[8] = {r0.x, r0.y, r0.z, r0.w, r1.x, r1.y, r1.z, r1.w};
        #pragma unroll
        for (int j = 0; j < 8; ++j) {
            sl[j] = cs[j] / SL;
            ent[j] = (unsigned int)cs[j] | ((unsigned int)rs[j] << 16);
            atomicAdd(&lhist[sl[j]], 1);
        }
    } else {
        for (int j = 0; j < n; ++j) {
            int c = col[e0 + j], r = row[e0 + j];
            sl[j] = c / SL;
            ent[j] = (unsigned int)c | ((unsigned int)r << 16);
            atomicAdd(&lhist[sl[j]], 1);
        }
    }
    __syncthreads();
    if (t == 0) {
        int cum = 0;
        #pragma unroll
        for (int s = 0; s < 8; ++s) { lbase[s] = cum; cum += lhist[s]; }
    }
    __syncthreads();
    if (t < 8) { gbase[t] = atomicAdd(&bcur[t], lhist[t]); lpos[t] = lbase[t]; }
    __syncthreads();
    for (int j = 0; j < n; ++j) {
        int p = atomicAdd(&lpos[sl[j]], 1);
        lent[p] = ent[j];
    }
    __syncthreads();
    int total = lbase[7] + lhist[7];
    for (int k = t; k < total; k += 256) {
        unsigned int e = lent[k];
        int s = 0;
        #pragma unroll
        for (int b = 1; b < 8; ++b) s = (k >= lbase[b]) ? b : s;
        bins[gbase[s] + (k - lbase[s])] = e;
    }
}

// fill phantom pad slots [offs[c]+deg[c], offs[c+1]) with node id N.
// XCD-localized; runs after convert (offs final), before csr_fill2 (deg intact).
__global__ __launch_bounds__(256) void padfill_x_kernel(
    const int* __restrict__ offs, const int* __restrict__ deg,
    unsigned short* __restrict__ srcs, int N) {
    int slice = blockIdx.x & 7;
    int SL = (N + 7) >> 3;
    int node = slice * SL + (int)(blockIdx.x >> 3) * THREADS + threadIdx.x;
    int nhi = min(N, slice * SL + SL);
    if (node >= nhi) return;
    int s = offs[node] + deg[node], e = offs[node + 1];
    for (int i = s; i < e; ++i) srcs[i] = (unsigned short)N;
}

// CSR scatter phase 2: block bid&7 = slice = XCD; streams ONLY its slice's
// bin (dense u32, no duplication), scatters into its L2-resident srcs slice
// -> full-line write merge. Grid-stride handles skew. deg is the countdown.
__global__ __launch_bounds__(256) void csr_fill2_kernel(
    const unsigned int* __restrict__ bins, const int* __restrict__ binoff,
    const int* __restrict__ offs, int* __restrict__ deg,
    unsigned short* __restrict__ srcs, int CPS) {
    int slice = blockIdx.x & 7;
    int chunk = blockIdx.x >> 3;
    int lo = binoff[slice], hi = binoff[slice + 1];
    for (int base = lo + chunk * 2048; base < hi; base += CPS * 2048) {
        int i0 = base + (int)threadIdx.x * 8;
        #pragma unroll
        for (int j = 0; j < 8; ++j) {
            int i = i0 + j;
            if (i < hi) {
                unsigned int e = bins[i];
                int c = (int)(e & 0xffffu);
                int r = (int)(e >> 16);
                int old = atomicSub(&deg[c], 1);
                srcs[offs[c] + old - 1] = (unsigned short)r;
            }
        }
    }
}

// merged: scanC (offs += bsum) + x fp32->fp16*dis (slice-major, stride N+1)
// + W1/W2/W3 -> fp16^T + phantom-row zeroing for Xs and Hs.
__global__ void convert_kernel(
    int* __restrict__ offs, const int* __restrict__ bsum, int Nfix,
    const float* __restrict__ X, const float* __restrict__ dis,
    _Float16* __restrict__ Xs, int total8, int IC,
    const float* __restrict__ W1, _Float16* __restrict__ W1t, int k1,   // k1=IC
    const float* __restrict__ W2, _Float16* __restrict__ W2t,
    const float* __restrict__ W3, _Float16* __restrict__ W3t,
    _Float16* __restrict__ Hs) {
    int i = blockIdx.x * THREADS + threadIdx.x;
    if (i < Nfix) {                         // scanC: add scanned block offsets
        offs[i] += bsum[i >> 10];
        return;
    }
    int j = i - Nfix;
    int Ms = Nfix + 1;                      // row stride incl. phantom
    if (j < total8) {
        int idx = j * 8;
        int node = idx / IC;
        int ch0  = idx % IC;
        float d = dis[node];
        float4 a = *(const float4*)&X[idx];
        float4 b = *(const float4*)&X[idx + 4];
        f16x8 o;
        o[0] = (_Float16)(d * a.x); o[1] = (_Float16)(d * a.y);
        o[2] = (_Float16)(d * a.z); o[3] = (_Float16)(d * a.w);
        o[4] = (_Float16)(d * b.x); o[5] = (_Float16)(d * b.y);
        o[6] = (_Float16)(d * b.z); o[7] = (_Float16)(d * b.w);
        int sw = IC >> 3;                   // slice width in f16 (IC=128 -> 16)
        int slice = ch0 / sw, within = ch0 % sw;
        *(f16x8*)&Xs[((size_t)slice * Ms + node) * sw + within] = o;
        return;
    }
    j -= total8;
    int n1 = k1 * 256;
    if (j < n1) {                 // W1 [k1 x 256] -> W1t [256 x k1]
        int k = j >> 8, n = j & 255;
        W1t[n * k1 + k] = (_Float16)W1[j];
        return;
    }
    j -= n1;
    if (j < 65536) {              // W2 [256 x 256]
        int k = j >> 8, n = j & 255;
        W2t[n * 256 + k] = (_Float16)W2[j];
        return;
    }
    j -= 65536;
    if (j < 65536) {              // W3
        int k = j >> 8, n = j & 255;
        W3t[n * 256 + k] = (_Float16)W3[j];
        return;
    }
    j -= 65536;
    {   // zero phantom rows: Xs 8 slices x (IC/8) f16, Hs 8 slices x 32 f16
        int swx = IC >> 3;
        int nx = 8 * swx;
        if (j < nx) {
            int slice = j / swx, wi = j % swx;
            Xs[((size_t)slice * Ms + Nfix) * swx + wi] = (_Float16)0.f;
            return;
        }
        j -= nx;
        if (j < 256) {
            int slice = j >> 5, wi = j & 31;
            Hs[((size_t)slice * Ms + Nfix) * 32 + wi] = (_Float16)0.f;
        }
    }
}

// ---- aggregation: a[i] = dis[i] * ( hs[i] + sum_{s in nbr} hs[s] ) ----------
// 8-way slice-major, XCD-pinned (bid&7 = slice = XCD; slice L2-resident).
// Dense node = slot mapping (R25 lesson: dense writes beat divergence-free
// waves). Padded edge lists (x8, phantom node N): indices load as one
// dwordx4 (8 x u16), prefetched one iteration ahead; 8 gathers in flight.
// R26: one-level f16 pairwise add (v_pk_add_f16) before f32 conversion:
// 16 pk + 32 cvt + 32 add per iter vs 64 cvt + 48 add. NT store.

template<int CH>   // full channel count: 128 or 256
__global__ __launch_bounds__(256) void aggregate_slice_kernel(
    const _Float16* __restrict__ X, const int* __restrict__ offs,
    const unsigned short* __restrict__ srcs, const float* __restrict__ dis,
    _Float16* __restrict__ A, int N) {
    constexpr int LPN = CH / 64;          // f16x8 lanes per node per slice (2 / 4)
    constexpr int NPB = 256 / LPN;        // nodes per block (128 / 64)
    int bid   = blockIdx.x;
    int slice = bid & 7;                  // round-robin -> XCD id
    int tile  = bid >> 3;
    int node  = tile * NPB + threadIdx.x / LPN;
    if (node >= N) return;
    int lane = threadIdx.x % LPN;
    size_t Ms = (size_t)N + 1;            // row stride incl. phantom
    const f16x8* Xv = (const f16x8*)X + (size_t)slice * Ms * LPN;
    f16x8 self = Xv[(size_t)node * LPN + lane];
    float acc[8], acc2[8];
    #pragma unroll
    for (int j = 0; j < 8; ++j) { acc[j] = (float)self[j]; acc2[j] = 0.f; }
    int s = offs[node], e = offs[node + 1];
    int nit = (e - s) >> 3;               // padded: always a multiple of 8
    if (nit > 0) {
        const u16x8* ip = (const u16x8*)&srcs[s];   // 16B-aligned (s % 8 == 0)
        u16x8 idx = ip[0];
        for (int it = 0; it < nit; ++it) {
            u16x8 nxt = ip[min(it + 1, nit - 1)];   // prefetch next 8 indices
            f16x8 v0 = Xv[(size_t)idx[0] * LPN + lane];
            f16x8 v1 = Xv[(size_t)idx[1] * LPN + lane];
            f16x8 v2 = Xv[(size_t)idx[2] * LPN + lane];
            f16x8 v3 = Xv[(size_t)idx[3] * LPN + lane];
            f16x8 v4 = Xv[(size_t)idx[4] * LPN + lane];
            f16x8 v5 = Xv[(size_t)idx[5] * LPN + lane];
            f16x8 v6 = Xv[(size_t)idx[6] * LPN + lane];
            f16x8 v7 = Xv[(size_t)idx[7] * LPN + lane];
            // one-level f16 pairwise add -> v_pk_add_f16 (2 ch/op)
            f16x8 s01 = v0 + v1;
            f16x8 s23 = v2 + v3;
            f16x8 s45 = v4 + v5;
            f16x8 s67 = v6 + v7;
            #pragma unroll
            for (int j = 0; j < 8; ++j) {
                acc[j]  += (float)s01[j] + (float)s23[j];
                acc2[j] += (float)s45[j] + (float)s67[j];
            }
            idx = nxt;
        }
    }
    float dn = dis[node];
    f16x8 o;
    #pragma unroll
    for (int j = 0; j < 8; ++j) o[j] = (_Float16)(dn * (acc[j] + acc2[j]));
    f16x8* Av = (f16x8*)A + (size_t)slice * Ms * LPN;
    __builtin_nontemporal_store(o, &Av[(size_t)node * LPN + lane]);
}

// ---- A-STATIONARY GEMM: H[m,:256] = relu( A[m,:K] @ W^T + bias ) -----------
// A is slice-major [8][Ms][K/8] (Ms = N+1 incl. phantom). Staged into LDS as
// row-major [64][K] (k = seg*8 identity), MFMA loop unchanged. 64-row tile,
// stride K+40, ONE barrier, barrier-free K-loop, B direct from global.
// MODE 1: write H (slice-major, dscaled). MODE 2: fused mean-pool epilogue.

template<int K, int MODE>
__global__ __launch_bounds__(256) void gemm_as_kernel(
    const _Float16* __restrict__ A, const _Float16* __restrict__ Bt,
    const float* __restrict__ bias, const float* __restrict__ dscale,
    _Float16* __restrict__ H, float* __restrict__ pooled,
    const int* __restrict__ batch, int M, int Ms) {
    constexpr int LSA = K + 40;               // ≡ 40 mod 64 -> even bank spread
    constexpr int KC = K / 32;
    constexpr int SPR = K / 8;                // 16B segs per row
    constexpr int SPS = K / 64;               // segs per slice (2 / 4)
    constexpr int SW  = K / 8;                // f16 per slice (16 / 32)
    __shared__ _Float16 As[64 * LSA];
    int tid = threadIdx.x;
    int m0 = blockIdx.x * 64;

    // stage A tile once (slice-major source; contiguous 64B runs per slice)
    {
        constexpr int RPI = 256 / SPR;        // 8 rows/iter (K=256), 16 (K=128)
        int r_in = tid % RPI;                 // consecutive lanes -> distinct rows
        int seg  = tid / RPI;
        int slice = seg / SPS, sub = seg % SPS;
        #pragma unroll
        for (int it = 0; it < 64 / RPI; ++it) {
            int r = it * RPI + r_in;
            int gr = m0 + r;
            uint4 v = make_uint4(0, 0, 0, 0);
            if (gr < M) v = *(const uint4*)&A[((size_t)slice * Ms + gr) * SW + sub * 8];
            *(uint4*)&As[r * LSA + seg * 8] = v;
        }
    }
    __syncthreads();

    int wid = tid >> 6, lane = tid & 63;
    int l16 = lane & 15, quad = lane >> 4;
    int wn = wid * 64;                        // this wave's 64 output cols

    f32x4 acc[4][4] = {};
    const _Float16* Bbase = Bt + (size_t)(wn + l16) * K + quad * 8;

    #pragma unroll
    for (int kc = 0; kc < KC; ++kc) {
        f16x8 bh[4];
        #pragma unroll
        for (int ni = 0; ni < 4; ++ni)
            bh[ni] = *(const f16x8*)&Bbase[(size_t)(ni * 16) * K + kc * 32];
        #pragma unroll
        for (int mi = 0; mi < 4; ++mi) {
            f16x8 ah = *(const f16x8*)&As[(mi * 16 + l16) * LSA + kc * 32 + quad * 8];
            #pragma unroll
            for (int ni = 0; ni < 4; ++ni)
                acc[mi][ni] = __builtin_amdgcn_mfma_f32_16x16x32_f16(ah, bh[ni], acc[mi][ni], 0, 0, 0);
        }
    }

    #pragma unroll
    for (int mi = 0; mi < 4; ++mi) {
        int rbase = m0 + mi * 16;
        int g0 = 0, g15 = 0;
        if (MODE == 2) {
            g0  = batch[min(rbase, M - 1)];
            g15 = batch[min(rbase + 15, M - 1)];
        }
        #pragma unroll
        for (int ni = 0; ni < 4; ++ni) {
            int col = wn + ni * 16 + l16;
            float bv = bias[col];
            if (MODE == 1) {
                // slice-major H: slice = col>>5 (256 cols, 32 f16/slice)
                size_t hbase = (size_t)(col >> 5) * Ms * 32 + (col & 31);
                #pragma unroll
                for (int r = 0; r < 4; ++r) {
                    int grow = rbase + quad * 4 + r;
                    if (grow < M) {
                        float v = fmaxf(acc[mi][ni][r] + bv, 0.f) * dscale[grow];
                        H[hbase + (size_t)grow * 32] = (_Float16)v;
                    }
                }
            } else {  // MODE == 2: fused mean-pool accumulation
                if (g0 == g15) {
                    float p = 0.f;
                    #pragma unroll
                    for (int r = 0; r < 4; ++r) {
                        int grow = rbase + quad * 4 + r;
                        float v = fmaxf(acc[mi][ni][r] + bv, 0.f);
                        p += (grow < M) ? v : 0.f;
                    }
                    p += __shfl_xor(p, 16);
                    p += __shfl_xor(p, 32);
                    if (quad == 0) atomicAdd(&pooled[g0 * 256 + col], p);
                } else {
                    #pragma unroll
                    for (int r = 0; r < 4; ++r) {
                        int grow = rbase + quad * 4 + r;
                        if (grow < M) {
                            float v = fmaxf(acc[mi][ni][r] + bv, 0.f);
                            atomicAdd(&pooled[batch[grow] * 256 + col], v);
                        }
                    }
                }
            }
        }
    }
}

// ---------------- FFN: relu(pooled/cnt @Wf+bf) @ Wo + bo, one block/graph ----

__global__ __launch_bounds__(256) void ffn_kernel(
    const float* __restrict__ pooled, const int* __restrict__ goff,
    const float* __restrict__ Wf, const float* __restrict__ bf,
    const float* __restrict__ Wo, const float* __restrict__ bo,
    float* __restrict__ out) {
    __shared__ float p[256];
    __shared__ float red[256];
    int g = blockIdx.x, t = threadIdx.x;
    int cnt = goff[g + 1] - goff[g];
    float inv = 1.f / (float)max(cnt, 1);
    p[t] = pooled[g * 256 + t] * inv;
    __syncthreads();
    float s = bf[t];
    #pragma unroll 8
    for (int k = 0; k < 256; ++k) s = fmaf(p[k], Wf[k * 256 + t], s);
    float gv = fmaxf(s, 0.f);
    red[t] = gv * Wo[t];
    __syncthreads();
    for (int o = 128; o > 0; o >>= 1) {
        if (t < o) red[t] += red[t + o];
        __syncthreads();
    }
    if (t == 0) out[g] = red[0] + bo[0];
}

// ---------------------------------------------------------------------------

extern "C" void kernel_launch(void* const* d_in, const int* in_sizes, int n_in,
                              void* d_out, int out_size, void* d_ws, size_t ws_size,
                              hipStream_t stream) {
    const float* x   = (const float*)d_in[0];
    const int*   ei  = (const int*)d_in[1];
    const int*   bat = (const int*)d_in[2];
    const float* W1  = (const float*)d_in[3];
    const float* b1  = (const float*)d_in[4];
    const float* W2  = (const float*)d_in[5];
    const float* b2  = (const float*)d_in[6];
    const float* W3  = (const float*)d_in[7];
    const float* b3  = (const float*)d_in[8];
    const float* Wf  = (const float*)d_in[9];
    const float* bf  = (const float*)d_in[10];
    const float* Wo  = (const float*)d_in[11];
    const float* bo  = (const float*)d_in[12];
    float* out = (float*)d_out;

    const int N  = in_sizes[2];        // 50000
    const int E  = in_sizes[1] / 2;    // 800000
    const int IC = in_sizes[0] / N;    // 128
    const int HID = 256;
    const int G  = out_size;           // 256
    const int Ms = N + 1;              // row stride incl. phantom node
    const int* row = ei;
    const int* col = ei + E;

    char* w = (char*)d_ws;
    size_t off = 0;
    auto alloc = [&](size_t bytes) -> void* {
        void* p = w + off;
        off += (bytes + 255) & ~(size_t)255;
        return p;
    };
    // deg and pooled adjacent -> one memset covers both
    int*   deg    = (int*)alloc((size_t)N * 4);
    float* pooled = (float*)alloc((size_t)G * HID * 4);
    float* dis    = (float*)alloc((size_t)N * 4);
    int*   offs   = (int*)alloc((size_t)(N + 1) * 4);
    unsigned short* srcs = (unsigned short*)alloc(((size_t)E + 7 * (size_t)N + 8) * 2);
    unsigned int* bins = (unsigned int*)alloc((size_t)(E + 8) * 4);
    int*   scnt   = (int*)alloc((size_t)8 * 4);
    int*   binoff = (int*)alloc((size_t)9 * 4);
    int*   bcur   = (int*)alloc((size_t)8 * 4);
    int*   goff   = (int*)alloc((size_t)(G + 1) * 4);
    int*   bsum   = (int*)alloc((size_t)64 * 4);
    _Float16* W1t = (_Float16*)alloc((size_t)HID * IC * 2);
    _Float16* W2t = (_Float16*)alloc((size_t)HID * HID * 2);
    _Float16* W3t = (_Float16*)alloc((size_t)HID * HID * 2);
    _Float16* Xs  = (_Float16*)alloc((size_t)Ms * IC * 2);
    _Float16* Ah  = (_Float16*)alloc((size_t)Ms * HID * 2);
    _Float16* Hs  = (_Float16*)alloc((size_t)Ms * HID * 2);
    (void)ws_size; (void)n_in;

    size_t zlen = (((size_t)N * 4 + 255) & ~(size_t)255) + (size_t)G * HID * 4;
    hipMemsetAsync(deg, 0, zlen, stream);

    degree_goff_kernel<<<(E + THREADS - 1) / THREADS, THREADS, 0, stream>>>(
        col, deg, E, bat, goff, N, G);

    int nb = (N + 1023) / 1024;   // 49 <= 64
    scanA_kernel<<<nb, 256, 0, stream>>>(deg, offs, bsum, dis, N);
    scanB_kernel<<<1, 64, 0, stream>>>(bsum, &offs[N], nb);

    slicecnt_kernel<<<8, 256, 0, stream>>>(deg, scnt, N);
    scan8_kernel<<<1, 64, 0, stream>>>(scnt, binoff, bcur);
    translate_bin_kernel<<<(E + 2047) / 2048, 256, 0, stream>>>(
        row, col, bins, bcur, E, N);

    int total8 = N * IC / 8;
    int conv_total = N + total8 + IC * HID + HID * HID + HID * HID + 8 * (IC / 8) + 256;
    convert_kernel<<<(conv_total + THREADS - 1) / THREADS, THREADS, 0, stream>>>(
        offs, bsum, N, x, dis, Xs, total8, IC, W1, W1t, IC, W2, W2t, W3, W3t, Hs);

    int SL = (N + 7) >> 3;
    int pf_tiles = (SL + THREADS - 1) / THREADS;
    padfill_x_kernel<<<pf_tiles * 8, THREADS, 0, stream>>>(offs, deg, srcs, N);
    int CPS = (E + 8 * 2048 - 1) / (8 * 2048);   // chunks per slice (~49)
    csr_fill2_kernel<<<CPS * 8, 256, 0, stream>>>(bins, binoff, offs, deg, srcs, CPS);

    int mtiles = (N + 63) / 64;   // 782
    // layer 1 (128 ch: 2 lanes/node/slice, 128 nodes/block)
    int nt1 = (N + 127) / 128;
    aggregate_slice_kernel<128><<<nt1 * 8, 256, 0, stream>>>(Xs, offs, srcs, dis, Ah, N);
    gemm_as_kernel<128, 1><<<mtiles, 256, 0, stream>>>(Ah, W1t, b1, dis, Hs, nullptr, nullptr, N, Ms);
    // layer 2 (256 ch: 4 lanes/node/slice, 64 nodes/block)
    int nt2 = (N + 63) / 64;
    aggregate_slice_kernel<256><<<nt2 * 8, 256, 0, stream>>>(Hs, offs, srcs, dis, Ah, N);
    gemm_as_kernel<256, 1><<<mtiles, 256, 0, stream>>>(Ah, W2t, b2, dis, Hs, nullptr, nullptr, N, Ms);
    // layer 3: GEMM fuses mean-pool (no H write)
    aggregate_slice_kernel<256><<<nt2 * 8, 256, 0, stream>>>(Hs, offs, srcs, dis, Ah, N);
    gemm_as_kernel<256, 2><<<mtiles, 256, 0, stream>>>(Ah, W3t, b3, nullptr, nullptr, pooled, bat, N, Ms);

    ffn_kernel<<<G, 256, 0, stream>>>(pooled, goff, Wf, bf, Wo, bo, out);
}

// Round 12
// 391.078 us; speedup vs baseline: 3.0389x; 1.0406x over previous
//
#include <hip/hip_runtime.h>
#include <hip/hip_bf16.h>
#include <hip/hip_fp16.h>

// ---------------------------------------------------------------------------
// GCN forward:  per layer  h' = ReLU( (Â h) @ W + b ),  aggregate-first.
// Node features stored fp16 PRE-SCALED by dis[i]:  hs[i] = dis[i]*h[i]
//   -> aggregation is a pure gather-SUM: a[i] = dis[i]*(hs[i] + sum hs[s])
// R17: 8-way channel slice, SLICE-MAJOR layout, XCD-pinned (bid&7 -> XCD).
//   Per-XCD gather footprint 3.2MB -> L2-resident (FETCH 159->32MB).
// R18: edge lists padded to x8 (phantom node N) + dwordx4 u16 index loads +
//   prefetch + 8-deep gather pipeline.
// R19: XCD-localized CSR scatter: each XCD streams the whole edge list
//   (L3-absorbed) but writes ONLY its 1/8 node-range of srcs (L2-resident
//   -> full-line write merge). Single kernel; 44us but overlaps neighbors.
// R23/R26 ledger: two-phase binning removed csr from the top-5 but its 4
//   extra serialized dispatches cost MORE total time than saved (R19 392 vs
//   R23 411). REVERTED to R19's csr path.
// R26 (kept): aggregate one-level f16 pairwise add (v_pk_add_f16, 2ch/op)
//   before f32 conversion — ~30% fewer VALU ops/iter, absmax unchanged.
// R24/R25 (reverted): order-indirection — scattered A-writes RMW-fetch cost
//   more than divergence saved.
// R15 GEMM: A-STATIONARY, 64-row LDS tile (stride K+40), ONE barrier,
// barrier-free K-loop, B direct from global (L2-hot). Layer-3 fuses pool.
// ---------------------------------------------------------------------------

#define THREADS 256
#define EPB 2048   // edges per csr_fill_x block (256 thr x 8)

typedef _Float16 f16x8 __attribute__((ext_vector_type(8)));
typedef float    f32x4 __attribute__((ext_vector_type(4)));
typedef unsigned short u16x8 __attribute__((ext_vector_type(8)));

// ---------------- setup kernels ----------------

// degree histogram (i<E) + graph offsets from sorted batch (i<N), one launch
__global__ void degree_goff_kernel(const int* __restrict__ col, int* __restrict__ deg, int E,
                                   const int* __restrict__ batch, int* __restrict__ goff,
                                   int N, int G) {
    int i = blockIdx.x * THREADS + threadIdx.x;
    if (i < E) atomicAdd(&deg[col[i]], 1);
    if (i < N) {
        int b1 = batch[i];
        int b0 = (i == 0) ? -1 : batch[i - 1];
        for (int g = b0 + 1; g <= b1; ++g) goff[g] = i;
        if (i == N - 1) {
            for (int g = b1 + 1; g <= G; ++g) goff[g] = N;
        }
    }
}

// scan phase A: per-block (1024 elems) exclusive scan of PADDED degrees
// (pad to multiple of 8) + block sum; also dis from REAL degree.
__global__ __launch_bounds__(256) void scanA_kernel(
    const int* __restrict__ in, int* __restrict__ out, int* __restrict__ bsum,
    float* __restrict__ dis, int n) {
    __shared__ int wsum[4];
    int i0 = blockIdx.x * 1024 + threadIdx.x * 4;
    int lane = threadIdx.x & 63, wid = threadIdx.x >> 6;
    int v0 = 0, v1 = 0, v2 = 0, v3 = 0;
    if (i0 + 3 < n) {
        int4 v = *(const int4*)&in[i0];
        v0 = v.x; v1 = v.y; v2 = v.z; v3 = v.w;
    } else {
        if (i0 + 0 < n) v0 = in[i0 + 0];
        if (i0 + 1 < n) v1 = in[i0 + 1];
        if (i0 + 2 < n) v2 = in[i0 + 2];
        if (i0 + 3 < n) v3 = in[i0 + 3];
    }
    // dis = rsqrt(deg+1) from real degree
    if (i0 + 0 < n) dis[i0 + 0] = rsqrtf((float)(v0 + 1));
    if (i0 + 1 < n) dis[i0 + 1] = rsqrtf((float)(v1 + 1));
    if (i0 + 2 < n) dis[i0 + 2] = rsqrtf((float)(v2 + 1));
    if (i0 + 3 < n) dis[i0 + 3] = rsqrtf((float)(v3 + 1));
    // pad degrees to multiple of 8 for the scan
    v0 = (v0 + 7) & ~7; v1 = (v1 + 7) & ~7;
    v2 = (v2 + 7) & ~7; v3 = (v3 + 7) & ~7;
    int s = v0 + v1 + v2 + v3;
    int inc = s;
    #pragma unroll
    for (int d = 1; d < 64; d <<= 1) {
        int t = __shfl_up(inc, d);
        if (lane >= d) inc += t;
    }
    if (lane == 63) wsum[wid] = inc;
    __syncthreads();
    int add = 0;
    for (int w = 0; w < wid; ++w) add += wsum[w];
    int ex = add + inc - s;
    if (i0 + 0 < n) out[i0 + 0] = ex;
    if (i0 + 1 < n) out[i0 + 1] = ex + v0;
    if (i0 + 2 < n) out[i0 + 2] = ex + v0 + v1;
    if (i0 + 3 < n) out[i0 + 3] = ex + v0 + v1 + v2;
    if (threadIdx.x == 255) bsum[blockIdx.x] = add + inc;  // block total
}

// scan phase B: 1 wave scans <=64 block sums; writes grand total to out[n].
__global__ void scanB_kernel(int* __restrict__ bsum, int* __restrict__ total_slot, int nb) {
    int lane = threadIdx.x;
    int v = (lane < nb) ? bsum[lane] : 0;
    int inc = v;
    #pragma unroll
    for (int d = 1; d < 64; d <<= 1) {
        int t = __shfl_up(inc, d);
        if (lane >= d) inc += t;
    }
    if (lane < nb) bsum[lane] = inc - v;   // exclusive
    if (lane == 63) *total_slot = inc;
}

// fill phantom pad slots [offs[c]+deg[c], offs[c+1]) with node id N.
// XCD-localized; runs after convert (offs final), before csr_fill (deg intact).
__global__ __launch_bounds__(256) void padfill_x_kernel(
    const int* __restrict__ offs, const int* __restrict__ deg,
    unsigned short* __restrict__ srcs, int N) {
    int slice = blockIdx.x & 7;
    int SL = (N + 7) >> 3;
    int node = slice * SL + (int)(blockIdx.x >> 3) * THREADS + threadIdx.x;
    int nhi = min(N, slice * SL + SL);
    if (node >= nhi) return;
    int s = offs[node] + deg[node], e = offs[node + 1];
    for (int i = s; i < e; ++i) srcs[i] = (unsigned short)N;
}

// CSR scatter, XCD-localized: block bid&7 = slice = XCD; each block scans a
// 2048-edge chunk (streaming col/row reads, duplicated 8x but L3-absorbed)
// and performs the atomicSub+store only for cols in its slice's node range.
// srcs writes stay in one XCD's L2 -> full-line merge. deg is the countdown.
__global__ __launch_bounds__(256) void csr_fill_x_kernel(
    const int* __restrict__ row, const int* __restrict__ col,
    const int* __restrict__ offs, int* __restrict__ deg,
    unsigned short* __restrict__ srcs, int E, int N) {
    int slice = blockIdx.x & 7;
    int SL = (N + 7) >> 3;
    int nlo = slice * SL;
    int nhi = min(N, nlo + SL);
    int e0 = (int)(blockIdx.x >> 3) * EPB + threadIdx.x * 8;
    if (e0 >= E) return;
    if (e0 + 8 <= E) {
        int4 c0 = *(const int4*)&col[e0];
        int4 c1 = *(const int4*)&col[e0 + 4];
        int4 r0 = *(const int4*)&row[e0];
        int4 r1 = *(const int4*)&row[e0 + 4];
        int cs[8] = {c0.x, c0.y, c0.z, c0.w, c1.x, c1.y, c1.z, c1.w};
        int rs[8] = {r0.x, r0.y, r0.z, r0.w, r1.x, r1.y, r1.z, r1.w};
        #pragma unroll
        for (int j = 0; j < 8; ++j) {
            int c = cs[j];
            if (c >= nlo && c < nhi) {
                int old = atomicSub(&deg[c], 1);
                srcs[offs[c] + old - 1] = (unsigned short)rs[j];
            }
        }
    } else {
        for (int j = 0; j < 8 && e0 + j < E; ++j) {
            int c = col[e0 + j];
            if (c >= nlo && c < nhi) {
                int old = atomicSub(&deg[c], 1);
                srcs[offs[c] + old - 1] = (unsigned short)row[e0 + j];
            }
        }
    }
}

// merged: scanC (offs += bsum) + x fp32->fp16*dis (slice-major, stride N+1)
// + W1/W2/W3 -> fp16^T + phantom-row zeroing for Xs and Hs.
__global__ void convert_kernel(
    int* __restrict__ offs, const int* __restrict__ bsum, int Nfix,
    const float* __restrict__ X, const float* __restrict__ dis,
    _Float16* __restrict__ Xs, int total8, int IC,
    const float* __restrict__ W1, _Float16* __restrict__ W1t, int k1,   // k1=IC
    const float* __restrict__ W2, _Float16* __restrict__ W2t,
    const float* __restrict__ W3, _Float16* __restrict__ W3t,
    _Float16* __restrict__ Hs) {
    int i = blockIdx.x * THREADS + threadIdx.x;
    if (i < Nfix) {                         // scanC: add scanned block offsets
        offs[i] += bsum[i >> 10];
        return;
    }
    int j = i - Nfix;
    int Ms = Nfix + 1;                      // row stride incl. phantom
    if (j < total8) {
        int idx = j * 8;
        int node = idx / IC;
        int ch0  = idx % IC;
        float d = dis[node];
        float4 a = *(const float4*)&X[idx];
        float4 b = *(const float4*)&X[idx + 4];
        f16x8 o;
        o[0] = (_Float16)(d * a.x); o[1] = (_Float16)(d * a.y);
        o[2] = (_Float16)(d * a.z); o[3] = (_Float16)(d * a.w);
        o[4] = (_Float16)(d * b.x); o[5] = (_Float16)(d * b.y);
        o[6] = (_Float16)(d * b.z); o[7] = (_Float16)(d * b.w);
        int sw = IC >> 3;                   // slice width in f16 (IC=128 -> 16)
        int slice = ch0 / sw, within = ch0 % sw;
        *(f16x8*)&Xs[((size_t)slice * Ms + node) * sw + within] = o;
        return;
    }
    j -= total8;
    int n1 = k1 * 256;
    if (j < n1) {                 // W1 [k1 x 256] -> W1t [256 x k1]
        int k = j >> 8, n = j & 255;
        W1t[n * k1 + k] = (_Float16)W1[j];
        return;
    }
    j -= n1;
    if (j < 65536) {              // W2 [256 x 256]
        int k = j >> 8, n = j & 255;
        W2t[n * 256 + k] = (_Float16)W2[j];
        return;
    }
    j -= 65536;
    if (j < 65536) {              // W3
        int k = j >> 8, n = j & 255;
        W3t[n * 256 + k] = (_Float16)W3[j];
        return;
    }
    j -= 65536;
    {   // zero phantom rows: Xs 8 slices x (IC/8) f16, Hs 8 slices x 32 f16
        int swx = IC >> 3;
        int nx = 8 * swx;
        if (j < nx) {
            int slice = j / swx, wi = j % swx;
            Xs[((size_t)slice * Ms + Nfix) * swx + wi] = (_Float16)0.f;
            return;
        }
        j -= nx;
        if (j < 256) {
            int slice = j >> 5, wi = j & 31;
            Hs[((size_t)slice * Ms + Nfix) * 32 + wi] = (_Float16)0.f;
        }
    }
}

// ---- aggregation: a[i] = dis[i] * ( hs[i] + sum_{s in nbr} hs[s] ) ----------
// 8-way slice-major, XCD-pinned (bid&7 = slice = XCD; slice L2-resident).
// Dense node = slot mapping (R25 lesson: dense writes beat divergence-free
// waves). Padded edge lists (x8, phantom node N): indices load as one
// dwordx4 (8 x u16), prefetched one iteration ahead; 8 gathers in flight.
// R26: one-level f16 pairwise add (v_pk_add_f16) before f32 conversion:
// 16 pk + 32 cvt + 32 add per iter vs 64 cvt + 48 add. NT store.

template<int CH>   // full channel count: 128 or 256
__global__ __launch_bounds__(256) void aggregate_slice_kernel(
    const _Float16* __restrict__ X, const int* __restrict__ offs,
    const unsigned short* __restrict__ srcs, const float* __restrict__ dis,
    _Float16* __restrict__ A, int N) {
    constexpr int LPN = CH / 64;          // f16x8 lanes per node per slice (2 / 4)
    constexpr int NPB = 256 / LPN;        // nodes per block (128 / 64)
    int bid   = blockIdx.x;
    int slice = bid & 7;                  // round-robin -> XCD id
    int tile  = bid >> 3;
    int node  = tile * NPB + threadIdx.x / LPN;
    if (node >= N) return;
    int lane = threadIdx.x % LPN;
    size_t Ms = (size_t)N + 1;            // row stride incl. phantom
    const f16x8* Xv = (const f16x8*)X + (size_t)slice * Ms * LPN;
    f16x8 self = Xv[(size_t)node * LPN + lane];
    float acc[8], acc2[8];
    #pragma unroll
    for (int j = 0; j < 8; ++j) { acc[j] = (float)self[j]; acc2[j] = 0.f; }
    int s = offs[node], e = offs[node + 1];
    int nit = (e - s) >> 3;               // padded: always a multiple of 8
    if (nit > 0) {
        const u16x8* ip = (const u16x8*)&srcs[s];   // 16B-aligned (s % 8 == 0)
        u16x8 idx = ip[0];
        for (int it = 0; it < nit; ++it) {
            u16x8 nxt = ip[min(it + 1, nit - 1)];   // prefetch next 8 indices
            f16x8 v0 = Xv[(size_t)idx[0] * LPN + lane];
            f16x8 v1 = Xv[(size_t)idx[1] * LPN + lane];
            f16x8 v2 = Xv[(size_t)idx[2] * LPN + lane];
            f16x8 v3 = Xv[(size_t)idx[3] * LPN + lane];
            f16x8 v4 = Xv[(size_t)idx[4] * LPN + lane];
            f16x8 v5 = Xv[(size_t)idx[5] * LPN + lane];
            f16x8 v6 = Xv[(size_t)idx[6] * LPN + lane];
            f16x8 v7 = Xv[(size_t)idx[7] * LPN + lane];
            // one-level f16 pairwise add -> v_pk_add_f16 (2 ch/op)
            f16x8 s01 = v0 + v1;
            f16x8 s23 = v2 + v3;
            f16x8 s45 = v4 + v5;
            f16x8 s67 = v6 + v7;
            #pragma unroll
            for (int j = 0; j < 8; ++j) {
                acc[j]  += (float)s01[j] + (float)s23[j];
                acc2[j] += (float)s45[j] + (float)s67[j];
            }
            idx = nxt;
        }
    }
    float dn = dis[node];
    f16x8 o;
    #pragma unroll
    for (int j = 0; j < 8; ++j) o[j] = (_Float16)(dn * (acc[j] + acc2[j]));
    f16x8* Av = (f16x8*)A + (size_t)slice * Ms * LPN;
    __builtin_nontemporal_store(o, &Av[(size_t)node * LPN + lane]);
}

// ---- A-STATIONARY GEMM: H[m,:256] = relu( A[m,:K] @ W^T + bias ) -----------
// A is slice-major [8][Ms][K/8] (Ms = N+1 incl. phantom). Staged into LDS as
// row-major [64][K] (k = seg*8 identity), MFMA loop unchanged. 64-row tile,
// stride K+40, ONE barrier, barrier-free K-loop, B direct from global.
// MODE 1: write H (slice-major, dscaled). MODE 2: fused mean-pool epilogue.

template<int K, int MODE>
__global__ __launch_bounds__(256) void gemm_as_kernel(
    const _Float16* __restrict__ A, const _Float16* __restrict__ Bt,
    const float* __restrict__ bias, const float* __restrict__ dscale,
    _Float16* __restrict__ H, float* __restrict__ pooled,
    const int* __restrict__ batch, int M, int Ms) {
    constexpr int LSA = K + 40;               // ≡ 40 mod 64 -> even bank spread
    constexpr int KC = K / 32;
    constexpr int SPR = K / 8;                // 16B segs per row
    constexpr int SPS = K / 64;               // segs per slice (2 / 4)
    constexpr int SW  = K / 8;                // f16 per slice (16 / 32)
    __shared__ _Float16 As[64 * LSA];
    int tid = threadIdx.x;
    int m0 = blockIdx.x * 64;

    // stage A tile once (slice-major source; contiguous 64B runs per slice)
    {
        constexpr int RPI = 256 / SPR;        // 8 rows/iter (K=256), 16 (K=128)
        int r_in = tid % RPI;                 // consecutive lanes -> distinct rows
        int seg  = tid / RPI;
        int slice = seg / SPS, sub = seg % SPS;
        #pragma unroll
        for (int it = 0; it < 64 / RPI; ++it) {
            int r = it * RPI + r_in;
            int gr = m0 + r;
            uint4 v = make_uint4(0, 0, 0, 0);
            if (gr < M) v = *(const uint4*)&A[((size_t)slice * Ms + gr) * SW + sub * 8];
            *(uint4*)&As[r * LSA + seg * 8] = v;
        }
    }
    __syncthreads();

    int wid = tid >> 6, lane = tid & 63;
    int l16 = lane & 15, quad = lane >> 4;
    int wn = wid * 64;                        // this wave's 64 output cols

    f32x4 acc[4][4] = {};
    const _Float16* Bbase = Bt + (size_t)(wn + l16) * K + quad * 8;

    #pragma unroll
    for (int kc = 0; kc < KC; ++kc) {
        f16x8 bh[4];
        #pragma unroll
        for (int ni = 0; ni < 4; ++ni)
            bh[ni] = *(const f16x8*)&Bbase[(size_t)(ni * 16) * K + kc * 32];
        #pragma unroll
        for (int mi = 0; mi < 4; ++mi) {
            f16x8 ah = *(const f16x8*)&As[(mi * 16 + l16) * LSA + kc * 32 + quad * 8];
            #pragma unroll
            for (int ni = 0; ni < 4; ++ni)
                acc[mi][ni] = __builtin_amdgcn_mfma_f32_16x16x32_f16(ah, bh[ni], acc[mi][ni], 0, 0, 0);
        }
    }

    #pragma unroll
    for (int mi = 0; mi < 4; ++mi) {
        int rbase = m0 + mi * 16;
        int g0 = 0, g15 = 0;
        if (MODE == 2) {
            g0  = batch[min(rbase, M - 1)];
            g15 = batch[min(rbase + 15, M - 1)];
        }
        #pragma unroll
        for (int ni = 0; ni < 4; ++ni) {
            int col = wn + ni * 16 + l16;
            float bv = bias[col];
            if (MODE == 1) {
                // slice-major H: slice = col>>5 (256 cols, 32 f16/slice)
                size_t hbase = (size_t)(col >> 5) * Ms * 32 + (col & 31);
                #pragma unroll
                for (int r = 0; r < 4; ++r) {
                    int grow = rbase + quad * 4 + r;
                    if (grow < M) {
                        float v = fmaxf(acc[mi][ni][r] + bv, 0.f) * dscale[grow];
                        H[hbase + (size_t)grow * 32] = (_Float16)v;
                    }
                }
            } else {  // MODE == 2: fused mean-pool accumulation
                if (g0 == g15) {
                    float p = 0.f;
                    #pragma unroll
                    for (int r = 0; r < 4; ++r) {
                        int grow = rbase + quad * 4 + r;
                        float v = fmaxf(acc[mi][ni][r] + bv, 0.f);
                        p += (grow < M) ? v : 0.f;
                    }
                    p += __shfl_xor(p, 16);
                    p += __shfl_xor(p, 32);
                    if (quad == 0) atomicAdd(&pooled[g0 * 256 + col], p);
                } else {
                    #pragma unroll
                    for (int r = 0; r < 4; ++r) {
                        int grow = rbase + quad * 4 + r;
                        if (grow < M) {
                            float v = fmaxf(acc[mi][ni][r] + bv, 0.f);
                            atomicAdd(&pooled[batch[grow] * 256 + col], v);
                        }
                    }
                }
            }
        }
    }
}

// ---------------- FFN: relu(pooled/cnt @Wf+bf) @ Wo + bo, one block/graph ----

__global__ __launch_bounds__(256) void ffn_kernel(
    const float* __restrict__ pooled, const int* __restrict__ goff,
    const float* __restrict__ Wf, const float* __restrict__ bf,
    const float* __restrict__ Wo, const float* __restrict__ bo,
    float* __restrict__ out) {
    __shared__ float p[256];
    __shared__ float red[256];
    int g = blockIdx.x, t = threadIdx.x;
    int cnt = goff[g + 1] - goff[g];
    float inv = 1.f / (float)max(cnt, 1);
    p[t] = pooled[g * 256 + t] * inv;
    __syncthreads();
    float s = bf[t];
    #pragma unroll 8
    for (int k = 0; k < 256; ++k) s = fmaf(p[k], Wf[k * 256 + t], s);
    float gv = fmaxf(s, 0.f);
    red[t] = gv * Wo[t];
    __syncthreads();
    for (int o = 128; o > 0; o >>= 1) {
        if (t < o) red[t] += red[t + o];
        __syncthreads();
    }
    if (t == 0) out[g] = red[0] + bo[0];
}

// ---------------------------------------------------------------------------

extern "C" void kernel_launch(void* const* d_in, const int* in_sizes, int n_in,
                              void* d_out, int out_size, void* d_ws, size_t ws_size,
                              hipStream_t stream) {
    const float* x   = (const float*)d_in[0];
    const int*   ei  = (const int*)d_in[1];
    const int*   bat = (const int*)d_in[2];
    const float* W1  = (const float*)d_in[3];
    const float* b1  = (const float*)d_in[4];
    const float* W2  = (const float*)d_in[5];
    const float* b2  = (const float*)d_in[6];
    const float* W3  = (const float*)d_in[7];
    const float* b3  = (const float*)d_in[8];
    const float* Wf  = (const float*)d_in[9];
    const float* bf  = (const float*)d_in[10];
    const float* Wo  = (const float*)d_in[11];
    const float* bo  = (const float*)d_in[12];
    float* out = (float*)d_out;

    const int N  = in_sizes[2];        // 50000
    const int E  = in_sizes[1] / 2;    // 800000
    const int IC = in_sizes[0] / N;    // 128
    const int HID = 256;
    const int G  = out_size;           // 256
    const int Ms = N + 1;              // row stride incl. phantom node
    const int* row = ei;
    const int* col = ei + E;

    char* w = (char*)d_ws;
    size_t off = 0;
    auto alloc = [&](size_t bytes) -> void* {
        void* p = w + off;
        off += (bytes + 255) & ~(size_t)255;
        return p;
    };
    // deg and pooled adjacent -> one memset covers both
    int*   deg    = (int*)alloc((size_t)N * 4);
    float* pooled = (float*)alloc((size_t)G * HID * 4);
    float* dis    = (float*)alloc((size_t)N * 4);
    int*   offs   = (int*)alloc((size_t)(N + 1) * 4);
    unsigned short* srcs = (unsigned short*)alloc(((size_t)E + 7 * (size_t)N + 8) * 2);
    int*   goff   = (int*)alloc((size_t)(G + 1) * 4);
    int*   bsum   = (int*)alloc((size_t)64 * 4);
    _Float16* W1t = (_Float16*)alloc((size_t)HID * IC * 2);
    _Float16* W2t = (_Float16*)alloc((size_t)HID * HID * 2);
    _Float16* W3t = (_Float16*)alloc((size_t)HID * HID * 2);
    _Float16* Xs  = (_Float16*)alloc((size_t)Ms * IC * 2);
    _Float16* Ah  = (_Float16*)alloc((size_t)Ms * HID * 2);
    _Float16* Hs  = (_Float16*)alloc((size_t)Ms * HID * 2);
    (void)ws_size; (void)n_in;

    size_t zlen = (((size_t)N * 4 + 255) & ~(size_t)255) + (size_t)G * HID * 4;
    hipMemsetAsync(deg, 0, zlen, stream);

    degree_goff_kernel<<<(E + THREADS - 1) / THREADS, THREADS, 0, stream>>>(
        col, deg, E, bat, goff, N, G);

    int nb = (N + 1023) / 1024;   // 49 <= 64
    scanA_kernel<<<nb, 256, 0, stream>>>(deg, offs, bsum, dis, N);
    scanB_kernel<<<1, 64, 0, stream>>>(bsum, &offs[N], nb);

    int total8 = N * IC / 8;
    int conv_total = N + total8 + IC * HID + HID * HID + HID * HID + 8 * (IC / 8) + 256;
    convert_kernel<<<(conv_total + THREADS - 1) / THREADS, THREADS, 0, stream>>>(
        offs, bsum, N, x, dis, Xs, total8, IC, W1, W1t, IC, W2, W2t, W3, W3t, Hs);

    int SL = (N + 7) >> 3;
    int pf_tiles = (SL + THREADS - 1) / THREADS;
    padfill_x_kernel<<<pf_tiles * 8, THREADS, 0, stream>>>(offs, deg, srcs, N);
    int cf_chunks = (E + EPB - 1) / EPB;
    csr_fill_x_kernel<<<cf_chunks * 8, THREADS, 0, stream>>>(row, col, offs, deg, srcs, E, N);

    int mtiles = (N + 63) / 64;   // 782
    // layer 1 (128 ch: 2 lanes/node/slice, 128 nodes/block)
    int nt1 = (N + 127) / 128;
    aggregate_slice_kernel<128><<<nt1 * 8, 256, 0, stream>>>(Xs, offs, srcs, dis, Ah, N);
    gemm_as_kernel<128, 1><<<mtiles, 256, 0, stream>>>(Ah, W1t, b1, dis, Hs, nullptr, nullptr, N, Ms);
    // layer 2 (256 ch: 4 lanes/node/slice, 64 nodes/block)
    int nt2 = (N + 63) / 64;
    aggregate_slice_kernel<256><<<nt2 * 8, 256, 0, stream>>>(Hs, offs, srcs, dis, Ah, N);
    gemm_as_kernel<256, 1><<<mtiles, 256, 0, stream>>>(Ah, W2t, b2, dis, Hs, nullptr, nullptr, N, Ms);
    // layer 3: GEMM fuses mean-pool (no H write)
    aggregate_slice_kernel<256><<<nt2 * 8, 256, 0, stream>>>(Hs, offs, srcs, dis, Ah, N);
    gemm_as_kernel<256, 2><<<mtiles, 256, 0, stream>>>(Ah, W3t, b3, nullptr, nullptr, pooled, bat, N, Ms);

    ffn_kernel<<<G, 256, 0, stream>>>(pooled, goff, Wf, bf, Wo, bo, out);
}